// Round 8
// baseline (222.353 us; speedup 1.0000x reference)
//
#include <hip/hip_runtime.h>

typedef __bf16 bf16;
typedef __bf16 bf16x4 __attribute__((ext_vector_type(4)));
typedef __bf16 bf16x8 __attribute__((ext_vector_type(8)));
typedef _Float16 f16;
typedef _Float16 f16x2 __attribute__((ext_vector_type(2)));
typedef _Float16 f16x4 __attribute__((ext_vector_type(4)));
typedef _Float16 f16x8 __attribute__((ext_vector_type(8)));
typedef float f32x4 __attribute__((ext_vector_type(4)));
typedef unsigned int u32x4 __attribute__((ext_vector_type(4)));

#define MFMA16 __builtin_amdgcn_mfma_f32_16x16x32_bf16
#define MFMA16H __builtin_amdgcn_mfma_f32_16x16x32_f16

// async 16B/lane global->LDS copy; HW scatters lane i to lds + i*16 (wave-uniform base)
__device__ __forceinline__ void async16(void* lds, const void* g) {
    __builtin_amdgcn_global_load_lds((const __attribute__((address_space(1))) unsigned int*)g,
                                     (__attribute__((address_space(3))) unsigned int*)lds, 16, 0, 0);
}

// packed f32x2 -> f16x2 (cvt_pkrtz returns __fp16-based vector; bit-cast to _Float16-based)
__device__ __forceinline__ f16x2 pkrtz(float a, float b) {
    return __builtin_bit_cast(f16x2, __builtin_amdgcn_cvt_pkrtz(a, b));
}

__device__ __forceinline__ float fdot2h(f16x2 a, f16x2 b, float c) {
#if __has_builtin(__builtin_amdgcn_fdot2)
    return __builtin_amdgcn_fdot2(a, b, c, false);
#else
    return c + (float)a[0] * (float)b[0] + (float)a[1] * (float)b[1];
#endif
}

// ---------------------------------------------------------------------------
// K0 "prep": weight cvt (blocks 0..255) + three activation transposes
// (s3: 256..767, s4: 768..1023, s5: 1024..1151).
__global__ __launch_bounds__(256) void k_prep(const float* __restrict__ qw, const float* __restrict__ kw,
                                              const float* __restrict__ vw, const float* __restrict__ ow,
                                              bf16* __restrict__ Wb,
                                              const float* __restrict__ s3, const float* __restrict__ s4,
                                              const float* __restrict__ s5,
                                              bf16* __restrict__ s3t, bf16* __restrict__ s45t) {
    __shared__ float T[64][65];
    int bx = blockIdx.x, t = threadIdx.x;
    if (bx < 256) {
        int tt = bx * 256 + t;
        const float* srcs[4] = {qw, kw, vw, ow};
        int which = tt >> 14;
        int idx = (tt & 16383) * 4;
        f32x4 v = *(const f32x4*)(srcs[which] + idx);
        bf16x4 o;
        o[0] = (bf16)v[0]; o[1] = (bf16)v[1]; o[2] = (bf16)v[2]; o[3] = (bf16)v[3];
        *(bf16x4*)(Wb + (size_t)which * 65536 + idx) = o;
        return;
    }
    const float* src; bf16* dst; int N, dstRows, rowOff, x, y, z;
    if (bx < 768)       { int i = bx - 256;  src = s3; dst = s3t;  N = 4096; dstRows = 4096; rowOff = 0;    x = i & 63; y = (i >> 6) & 3; z = i >> 8; }
    else if (bx < 1024) { int i = bx - 768;  src = s4; dst = s45t; N = 2048; dstRows = 3072; rowOff = 0;    x = i & 31; y = (i >> 5) & 3; z = i >> 7; }
    else                { int i = bx - 1024; src = s5; dst = s45t; N = 1024; dstRows = 3072; rowOff = 2048; x = i & 15; y = (i >> 4) & 3; z = i >> 6; }
    int c0 = y * 64, n0 = x * 64, b = z;
    const float* s = src + ((size_t)b * 256 + c0) * N + n0;
#pragma unroll
    for (int i = 0; i < 4; i++) {
        int flat = i * 256 + t;
        int row = flat >> 4;
        int col = (flat & 15) * 4;
        f32x4 v = *(const f32x4*)(s + (size_t)row * N + col);
        T[row][col + 0] = v[0]; T[row][col + 1] = v[1];
        T[row][col + 2] = v[2]; T[row][col + 3] = v[3];
    }
    __syncthreads();
#pragma unroll
    for (int i = 0; i < 4; i++) {
        int flat = i * 256 + t;
        int nrow = flat >> 4;
        int c4 = (flat & 15) * 4;
        bf16x4 o;
        o[0] = (bf16)T[c4 + 0][nrow]; o[1] = (bf16)T[c4 + 1][nrow];
        o[2] = (bf16)T[c4 + 2][nrow]; o[3] = (bf16)T[c4 + 3][nrow];
        *(bf16x4*)(dst + ((size_t)(b * dstRows + rowOff + n0 + nrow)) * 256 + c0 + c4) = o;
    }
}

// ---------------------------------------------------------------------------
// K1 "qkv": Q blocks 0..511 (mode 0), K 512..895 (mode 1), V 896..1279 (mode 2).
// mode 0: Q bf16 [bh][n][32], pre-scaled by 32^-.5*log2e.
// mode 1: K bf16 [bh][n'][32], n' row-permuted within 32-blocks.
// mode 2: V f16 [bh][32 d][3072 kn], kn permuted per 64-chunk by d-keyed XOR;
// R15: operand-swapped MFMA (D^T) -> 4x f16x4 stores instead of 16 scalar.
// R13: counted-vmcnt pipeline (raw s_barrier + vmcnt(2)).
__global__ __launch_bounds__(256) void k_qkv(const bf16* __restrict__ Wb,
                                             const bf16* __restrict__ s3t, const bf16* __restrict__ s45t,
                                             const float* __restrict__ qb, const float* __restrict__ kb,
                                             const float* __restrict__ vb,
                                             bf16* __restrict__ Qb, bf16* __restrict__ Kb,
                                             f16* __restrict__ Vtb, float qscale) {
    int i = blockIdx.x;
    int mode, n0, m0, b, Nrows;
    const bf16 *A, *Bt; const float* bias; float oscale = 1.0f;
    if (i < 512) {
        mode = 0; A = Wb; Bt = s3t; bias = qb; Nrows = 4096; oscale = qscale;
        n0 = (i & 63) * 64; m0 = ((i >> 6) & 3) * 64; b = i >> 8;
    } else if (i < 896) {
        unsigned j = i - 512;
        mode = 1; A = Wb + 65536; Bt = s45t; bias = kb; Nrows = 3072;
        n0 = (j % 48u) * 64; unsigned rr = j / 48u; m0 = (rr & 3) * 64; b = rr >> 2;
    } else {
        unsigned j = i - 896;
        mode = 2; A = Wb + 131072; Bt = s45t; bias = vb; Nrows = 3072;
        n0 = (j % 48u) * 64; unsigned rr = j / 48u; m0 = (rr & 3) * 64; b = rr >> 2;
    }
    __shared__ __align__(16) bf16 As[2][64 * 32];
    __shared__ __align__(16) bf16 Bs[2][64 * 32];
    int t = threadIdx.x;
    int w = t >> 6, lane = t & 63;
    int lrow = lane & 15, lk = lane >> 4;
    f32x4 acc[4] = {};
    const bf16* Ag = A + (size_t)(m0 + w * 16 + (lane >> 2)) * 256 + (lane & 3) * 8;
    const bf16* Bg = Bt + ((size_t)b * Nrows + n0 + w * 16 + (lane >> 2)) * 256 + (lane & 3) * 8;
    async16(&As[0][w * 512], Ag);
    async16(&Bs[0][w * 512], Bg);
    async16(&As[1][w * 512], Ag + 32);
    async16(&Bs[1][w * 512], Bg + 32);
    for (int s8 = 0; s8 < 8; ++s8) {
        int buf = s8 & 1;
        if (s8 < 7) asm volatile("s_waitcnt vmcnt(2)" ::: "memory");
        else        asm volatile("s_waitcnt vmcnt(0)" ::: "memory");
        __builtin_amdgcn_s_barrier();
        __builtin_amdgcn_sched_barrier(0);
        bf16x8 af = *(const bf16x8*)(&As[buf][(w * 16 + lrow) * 32 + lk * 8]);
#pragma unroll
        for (int ct = 0; ct < 4; ct++) {
            bf16x8 bfr = *(const bf16x8*)(&Bs[buf][(ct * 16 + lrow) * 32 + lk * 8]);
            if (mode == 2) acc[ct] = MFMA16(bfr, af, acc[ct], 0, 0, 0);   // D^T: rows=n, cols=o
            else           acc[ct] = MFMA16(af, bfr, acc[ct], 0, 0, 0);   // rows=o, cols=n
        }
        __builtin_amdgcn_s_barrier();
        if (s8 < 6) {
            async16(&As[buf][w * 512], Ag + (s8 + 2) * 32);
            async16(&Bs[buf][w * 512], Bg + (s8 + 2) * 32);
        }
    }
    // C/D layout: col = lane&15, row = (lane>>4)*4 + reg  [verified m89/m91]
    if (mode == 2) {
        // lane: o = m0 + w*16 + lrow (fixed), n = n0 + ct*16 + lk*4 + j (consecutive)
        int o = m0 + w * 16 + lrow;
        int head = o >> 5;
        int dd = o & 31;
        float bs = bias[o];
        int key = dd & 7;
        f16* vrow = Vtb + ((size_t)(b * 8 + head) * 32 + dd) * 3072;
#pragma unroll
        for (int ct = 0; ct < 4; ct++) {
            int g = ct * 2 + (lk >> 1);                       // 8-elem granule of n&63
            int col = n0 + ((g ^ key) << 3) + (lk & 1) * 4;   // XOR-permuted position
            f16x4 pv;
#pragma unroll
            for (int j = 0; j < 4; j++) pv[j] = (f16)(acc[ct][j] + bs);
            *(f16x4*)(vrow + col) = pv;
        }
    } else {
        int o0 = m0 + w * 16 + lk * 4;
        f32x4 b4 = *(const f32x4*)(bias + o0);
        int head = o0 >> 5;
#pragma unroll
        for (int ct = 0; ct < 4; ct++) {
            int n = n0 + ct * 16 + lrow;
            if (mode == 0) {
                int dd = o0 & 31;
                bf16x4 pv;
#pragma unroll
                for (int j = 0; j < 4; j++) pv[j] = (bf16)((acc[ct][j] + b4[j]) * oscale);
                *(bf16x4*)(Qb + ((size_t)(b * 8 + head) * 4096 + n) * 32 + dd) = pv;
            } else {
                int dd = o0 & 31;
                int u = n & 31;
                int np = (n & ~31) | (((u >> 2) & 1) << 4) | ((u >> 3) << 2) | (u & 3);
                bf16x4 pv;
#pragma unroll
                for (int j = 0; j < 4; j++) pv[j] = (bf16)(acc[ct][j] + b4[j]);
                *(bf16x4*)(Kb + ((size_t)(b * 8 + head) * 3072 + np) * 32 + dd) = pv;
            }
        }
    }
}

// ---------------------------------------------------------------------------
// K2: attention. S^T = K·Q^T (bf16 16x16x32); exp2'd C/D regs form a K=32 f16
// B-operand for PV (V^T as A): out^T[d][q] += V^T·P^T.
// R14: per-wave q-tile 64 (4 q-groups) — each kf/vf LDS read feeds 16 MFMAs.
// R17: OCCUPANCY 4 -> 6 blocks/CU (16 -> 24 waves/CU). R15/R16 counters:
// Occ 35%, MfmaUtil 22, VALU 40, HBM 6 — per-wave dep chains with only
// ~2.75 waves/SIMD leave every pipe idle most of the time; R16's chunk
// rotation proved phase-reordering alone is null, so the lever is TLP.
// KVBLK 128->64 (LDS 16.9KB, 6 fit in 160KB), split-kn 4->6 (512 kn/block,
// grid 16bh x 6sp x 16q = 1536 = exactly 6/CU), launch_bounds (256,6)
// (VGPR cap 85; measured 64). Counted-vmcnt dbuf: 2 loads/tile, vmcnt(2).
// XCD swizzle: combo = id%96 fastest -> each XCD hosts 12 combos (2 bh).
__global__ __launch_bounds__(256, 6) void k_attn(const bf16* __restrict__ Q, const bf16* __restrict__ K,
                                                 const f16* __restrict__ Vt,
                                                 f16* __restrict__ Opart, float* __restrict__ Lsum) {
    int id = blockIdx.x;
    int c96 = id % 96;
    int bh = c96 & 15;
    int sp = c96 >> 4;          // 0..5
    int q0 = (id / 96) * 256;
    int kn0 = sp * 512;
    int t = threadIdx.x, w = t >> 6, lane = t & 63;
    int lrow = lane & 15, lk = lane >> 4;
    __shared__ __align__(16) char smem[16896];
    bf16* Ks = (bf16*)smem;           // [2][64*32] bf16 (buf stride 2048 elems)
    f16* Vs = (f16*)(smem + 8192);    // [2][32*64] f16 (buf stride 2048)
    f16* Tq = (f16*)smem;             // epilogue: per-wave 32 x 66 (aliases Ks/Vs)
    const bf16* kbase = K + (size_t)bh * 3072 * 32;
    const f16* vbase = Vt + (size_t)bh * 32 * 3072;
    const bf16* kg = kbase + (size_t)(kn0 + w * 16 + (lane >> 2)) * 32 + (lane & 3) * 8;
    const f16* vg = vbase + (size_t)(w * 8 + (lane >> 3)) * 3072 + kn0 + (lane & 7) * 8;
    // Q as B-operand: B[k=d=lk*8+j][n=q=lrow], one frag per 16-q group
    bf16x8 aq[4];
#pragma unroll
    for (int qg = 0; qg < 4; ++qg)
        aq[qg] = *(const bf16x8*)(Q + ((size_t)bh * 4096 + q0 + w * 64 + qg * 16 + lrow) * 32 + lk * 8);
    f32x4 accO[4][2] = {};   // [q-group][d-half], out^T: row=d_local, col=q
    float lsum[4] = {0.f, 0.f, 0.f, 0.f};
    f32x4 zero = {};
    f16x2 one2; one2[0] = (f16)1.f; one2[1] = (f16)1.f;
    int vkey = lrow & 7;     // V image XOR key = d&7 (same for both d-halves)
    // prologue: stage tiles 0 and 1 (2 loads each: K, V)
    async16(Ks + w * 512, kg);
    async16(Vs + w * 512, vg);
    async16(Ks + 2048 + w * 512, kg + 64 * 32);
    async16(Vs + 2048 + w * 512, vg + 64);
    for (int c = 0; c < 8; ++c) {
        int buf = c & 1;
        // wait for THIS tile's 2 loads; next tile's 2 stay in flight
        if (c < 7) asm volatile("s_waitcnt vmcnt(2)" ::: "memory");
        else       asm volatile("s_waitcnt vmcnt(0)" ::: "memory");
        __builtin_amdgcn_s_barrier();
        __builtin_amdgcn_sched_barrier(0);
        const bf16* ksb = Ks + buf * 2048;
        const f16* vsb = Vs + buf * 2048;
#pragma unroll
        for (int p = 0; p < 2; ++p) {   // two 32-kn chunks
            bf16x8 kf0 = *(const bf16x8*)(ksb + (p * 32 + lrow) * 32 + lk * 8);
            bf16x8 kf1 = *(const bf16x8*)(ksb + (p * 32 + 16 + lrow) * 32 + lk * 8);
            int gran = ((p << 2) | lk) ^ vkey;
            f16x8 vf0 = *(const f16x8*)(vsb + lrow * 64 + (gran << 3));
            f16x8 vf1 = *(const f16x8*)(vsb + (16 + lrow) * 64 + (gran << 3));
#pragma unroll
            for (int qg = 0; qg < 4; ++qg) {   // kf/vf shared across 4 qg
                f32x4 s0 = MFMA16(kf0, aq[qg], zero, 0, 0, 0);
                f32x4 s1 = MFMA16(kf1, aq[qg], zero, 0, 0, 0);
                f16x2 h0 = pkrtz(__builtin_amdgcn_exp2f(s0[0]), __builtin_amdgcn_exp2f(s0[1]));
                f16x2 h1 = pkrtz(__builtin_amdgcn_exp2f(s0[2]), __builtin_amdgcn_exp2f(s0[3]));
                f16x2 h2 = pkrtz(__builtin_amdgcn_exp2f(s1[0]), __builtin_amdgcn_exp2f(s1[1]));
                f16x2 h3 = pkrtz(__builtin_amdgcn_exp2f(s1[2]), __builtin_amdgcn_exp2f(s1[3]));
                f16x8 pk;
                pk[0] = h0[0]; pk[1] = h0[1]; pk[2] = h1[0]; pk[3] = h1[1];
                pk[4] = h2[0]; pk[5] = h2[1]; pk[6] = h3[0]; pk[7] = h3[1];
                lsum[qg] = fdot2h(h0, one2, lsum[qg]);
                lsum[qg] = fdot2h(h1, one2, lsum[qg]);
                lsum[qg] = fdot2h(h2, one2, lsum[qg]);
                lsum[qg] = fdot2h(h3, one2, lsum[qg]);
                accO[qg][0] = MFMA16H(vf0, pk, accO[qg][0], 0, 0, 0);
                accO[qg][1] = MFMA16H(vf1, pk, accO[qg][1], 0, 0, 0);
            }
        }
        // all LDS reads consumed above; separate read-phase from overwrite
        __builtin_amdgcn_s_barrier();
        if (c < 6) {
            async16(Ks + buf * 2048 + w * 512, kg + (size_t)(c + 2) * 64 * 32);
            async16(Vs + buf * 2048 + w * 512, vg + (c + 2) * 64);
        }
    }
    // L: reduce per-lane partials over lk (lanes lrow, lrow+16, +32, +48)
    int sb = sp * 16 + bh;
#pragma unroll
    for (int qg = 0; qg < 4; ++qg) {
        lsum[qg] += __shfl_xor(lsum[qg], 16, 64);
        lsum[qg] += __shfl_xor(lsum[qg], 32, 64);
    }
    if (lane < 16) {
#pragma unroll
        for (int qg = 0; qg < 4; ++qg)
            Lsum[(size_t)sb * 4096 + q0 + w * 64 + qg * 16 + lane] = lsum[qg];
    }
    // O epilogue: same-wave LDS transpose [d][q] -> coalesced [q][d] f16 stores
    // (final loop barrier guarantees all waves' LDS reads are done)
    f16* tw = Tq + w * 2112;   // 32 d-rows x 66 (pad)
#pragma unroll
    for (int qg = 0; qg < 4; ++qg)
#pragma unroll
        for (int dh = 0; dh < 2; ++dh)
#pragma unroll
            for (int i = 0; i < 4; ++i)
                tw[(dh * 16 + lk * 4 + i) * 66 + qg * 16 + lrow] = (f16)accO[qg][dh][i];
    int q4 = (lane & 15) * 4, dgrp = (lane >> 4) * 8;
#pragma unroll
    for (int qq = 0; qq < 4; ++qq) {
        f16x8 ov;
#pragma unroll
        for (int dj = 0; dj < 8; ++dj) ov[dj] = tw[(dgrp + dj) * 66 + q4 + qq];
        *(f16x8*)(Opart + ((size_t)sb * 4096 + q0 + w * 64 + q4 + qq) * 32 + dgrp) = ov;
    }
}

// ---------------------------------------------------------------------------
// K3 "oln": o-projection + split-kn combine + bias + residual + LayerNorm +
// output transpose. Block = 32 q x 256 c. R15: hoisted combine into Bs (once)
// + counted-vmcnt async16 A-staging. R17: combine reads 6 split-kn partials.
__global__ __launch_bounds__(256) void k_oln(const bf16* __restrict__ A, const f16* __restrict__ Opart,
                                             const float* __restrict__ Ls, const float* __restrict__ bias,
                                             const bf16* __restrict__ s3t,
                                             const float* __restrict__ lnw, const float* __restrict__ lnb,
                                             float* __restrict__ out) {
    int i = blockIdx.x;
    int b = i >> 7, n0 = (i & 127) * 32;
    __shared__ __align__(16) char smem[50944];
    bf16* As = (bf16*)smem;                 // [2][256*32] bf16 = 32768 B (async16 dest, linear)
    bf16* Bs = (bf16*)(smem + 32768);       // 32 x 264 bf16 = 16896 B (GEMM phase)
    float* T = (float*)smem;                // 32 x 257 f32 = 32896 B (LN phase, aliases As+)
    float* ps = (float*)(smem + 49664);     // [4 w][32 n]
    float* pq = (float*)(smem + 50176);     // [4 w][32 n]
    float* mu_s = (float*)(smem + 50688);   // [32]
    float* rs_s = (float*)(smem + 50816);   // [32]
    int t = threadIdx.x, w = t >> 6, lane = t & 63;
    int lrow = lane & 15, lk = lane >> 4;
    f32x4 acc[4][2] = {};                   // [mt: c-64-block][ct: 16-q group]
    const size_t SPS = (size_t)16 * 4096 * 32;   // Opart sp stride (elems)
    // A staging: granule f = (w*4+s)*64 + lane; row = f>>2, col-granule = f&3.
    // LDS elem offset = f*8 (linear) -> [row][32 c] layout.
#define STAGE_A(buf_, kc_)                                                              \
    {                                                                                   \
        _Pragma("unroll")                                                               \
        for (int s_ = 0; s_ < 4; ++s_) {                                                \
            int f_ = (w * 4 + s_) * 64 + lane;                                          \
            async16(As + (buf_) * 8192 + f_ * 8,                                        \
                    A + (size_t)(f_ >> 2) * 256 + (kc_) + (f_ & 3) * 8);                \
        }                                                                               \
    }
    STAGE_A(0, 0)
    STAGE_A(1, 32)
    // hoisted combine: B[32 q][256 c] = (sum_sp Opart) / (sum_sp Ls)
    {
        int rB = t >> 3;
        int q = n0 + rB;
        int c4 = (t & 7) * 4;
#pragma unroll
        for (int cg8 = 0; cg8 < 8; ++cg8) {
            int bh = b * 8 + cg8;
            float l = 0.f;
#pragma unroll
            for (int sp = 0; sp < 6; ++sp) l += Ls[(size_t)(sp * 16 + bh) * 4096 + q];
            float rl = 1.0f / l;
            const f16* obp = Opart + ((size_t)bh * 4096 + q) * 32 + c4;
            f32x4 sv = {};
#pragma unroll
            for (int sp = 0; sp < 6; ++sp) {
                f16x4 av = *(const f16x4*)(obp + sp * SPS);
#pragma unroll
                for (int j = 0; j < 4; ++j) sv[j] += (float)av[j];
            }
            bf16x4 bb;
#pragma unroll
            for (int j = 0; j < 4; ++j) bb[j] = (bf16)(sv[j] * rl);
            *(bf16x4*)(Bs + rB * 264 + cg8 * 32 + c4) = bb;
        }
    }
    asm volatile("s_waitcnt lgkmcnt(0)" ::: "memory");   // Bs writes drained pre-barrier
    for (int s8 = 0; s8 < 8; ++s8) {
        int buf = s8 & 1;
        int kc = s8 * 32;
        if (s8 < 7) asm volatile("s_waitcnt vmcnt(4)" ::: "memory");
        else        asm volatile("s_waitcnt vmcnt(0)" ::: "memory");
        __builtin_amdgcn_s_barrier();
        __builtin_amdgcn_sched_barrier(0);
#pragma unroll
        for (int ct = 0; ct < 2; ++ct) {
            bf16x8 bfr = *(const bf16x8*)(Bs + (ct * 16 + lrow) * 264 + kc + lk * 8);
#pragma unroll
            for (int mt = 0; mt < 4; ++mt) {
                bf16x8 af = *(const bf16x8*)(As + buf * 8192 + (mt * 64 + w * 16 + lrow) * 32 + lk * 8);
                acc[mt][ct] = MFMA16(af, bfr, acc[mt][ct], 0, 0, 0);
            }
        }
        __builtin_amdgcn_s_barrier();
        if (s8 < 6) STAGE_A(buf, (s8 + 2) * 32)
    }
#undef STAGE_A
    // epilogue: bias + residual; write raw values to T; accumulate LN stats
    float wsum[2] = {0.f, 0.f}, wsq[2] = {0.f, 0.f};
#pragma unroll
    for (int ct = 0; ct < 2; ++ct) {
        int n = ct * 16 + lrow;
#pragma unroll
        for (int mt = 0; mt < 4; ++mt) {
            int c0 = mt * 64 + w * 16 + lk * 4;
            f32x4 b4 = *(const f32x4*)(bias + c0);
            bf16x4 rv = *(const bf16x4*)(s3t + ((size_t)b * 4096 + n0 + n) * 256 + c0);
#pragma unroll
            for (int j = 0; j < 4; ++j) {
                float v = acc[mt][ct][j] + b4[j] + (float)rv[j];
                T[n * 257 + c0 + j] = v;
                wsum[ct] += v;
                wsq[ct] += v * v;
            }
        }
    }
#pragma unroll
    for (int ct = 0; ct < 2; ++ct) {
        wsum[ct] += __shfl_xor(wsum[ct], 16, 64);
        wsum[ct] += __shfl_xor(wsum[ct], 32, 64);
        wsq[ct] += __shfl_xor(wsq[ct], 16, 64);
        wsq[ct] += __shfl_xor(wsq[ct], 32, 64);
    }
    if (lk == 0) {
#pragma unroll
        for (int ct = 0; ct < 2; ++ct) {
            ps[w * 32 + ct * 16 + lrow] = wsum[ct];
            pq[w * 32 + ct * 16 + lrow] = wsq[ct];
        }
    }
    __syncthreads();
    if (t < 32) {
        float S = ps[t] + ps[32 + t] + ps[64 + t] + ps[96 + t];
        float Q2 = pq[t] + pq[32 + t] + pq[64 + t] + pq[96 + t];
        float m = S * (1.0f / 256.0f);
        mu_s[t] = m;
        rs_s[t] = rsqrtf(Q2 * (1.0f / 256.0f) - m * m + 1e-5f);
    }
    __syncthreads();
    // write out[b][c][n0..n0+31], coalesced along n
    int cb = t >> 3, n4 = (t & 7) * 4;
#pragma unroll
    for (int cc8 = 0; cc8 < 8; ++cc8) {
        int c = cb + cc8 * 32;
        float wv = lnw[c], bv = lnb[c];
        f32x4 o;
#pragma unroll
        for (int k2 = 0; k2 < 4; ++k2)
            o[k2] = (T[(n4 + k2) * 257 + c] - mu_s[n4 + k2]) * rs_s[n4 + k2] * wv + bv;
        *(f32x4*)(out + ((size_t)b * 256 + c) * 4096 + n0 + n4) = o;
    }
}

// ---------------------------------------------------------------------------
extern "C" void kernel_launch(void* const* d_in, const int* in_sizes, int n_in,
                              void* d_out, int out_size, void* d_ws, size_t ws_size,
                              hipStream_t stream) {
    const float* s3  = (const float*)d_in[0];
    const float* s4  = (const float*)d_in[1];
    const float* s5  = (const float*)d_in[2];
    const float* qw  = (const float*)d_in[3];
    const float* qb  = (const float*)d_in[4];
    const float* kw  = (const float*)d_in[5];
    const float* kb  = (const float*)d_in[6];
    const float* vw  = (const float*)d_in[7];
    const float* vb  = (const float*)d_in[8];
    const float* ow  = (const float*)d_in[9];
    const float* ob  = (const float*)d_in[10];
    const float* lnw = (const float*)d_in[11];
    const float* lnb = (const float*)d_in[12];
    float* out = (float*)d_out;
    char* ws = (char*)d_ws;

    // workspace layout (~44 MB peak):
    bf16* Wb    = (bf16*)(ws);                          // 512 KB @ 0
    bf16* s3t   = (bf16*)(ws + (512ull << 10));         // 4 MB  @ 0.5 MB (live till k_oln)
    bf16* s45t  = (bf16*)(ws + (4608ull << 10));        // 3 MB  @ 4.5 MB
    bf16* Qb    = (bf16*)(ws + (7680ull << 10));        // 4 MB  @ 7.5 MB
    bf16* Kb    = Qb + (2ull * 8 * 4096 * 32);          // 3 MB  @ 11.5 MB
    f16*  Vtb   = (f16*)(Kb + (2ull * 8 * 3072 * 32));  // 3 MB  @ 14.5 MB
    f16*  Opart = (f16*)(ws + (17920ull << 10));        // 24 MB @ 17.5 MB (f16 [6sp][16bh][4096q][32d])
    float* Lsum = (float*)(ws + (42496ull << 10));      // 1.5 MB @ 41.5 MB

    const float qscale = 0.17677669529663688f * 1.4426950408889634f;  // 32^-0.5 * log2(e)

    k_prep<<<1152, 256, 0, stream>>>(qw, kw, vw, ow, Wb, s3, s4, s5, s3t, s45t);
    k_qkv<<<1280, 256, 0, stream>>>(Wb, s3t, s45t, qb, kb, vb, Qb, Kb, Vtb, qscale);
    k_attn<<<1536, 256, 0, stream>>>(Qb, Kb, Vtb, Opart, Lsum);
    k_oln<<<256, 256, 0, stream>>>(Wb + 196608, Opart, Lsum, ob, s3t, lnw, lnb, out);
}

// Round 9
// 142.206 us; speedup vs baseline: 1.5636x; 1.5636x over previous
//
#include <hip/hip_runtime.h>

typedef __bf16 bf16;
typedef __bf16 bf16x4 __attribute__((ext_vector_type(4)));
typedef __bf16 bf16x8 __attribute__((ext_vector_type(8)));
typedef _Float16 f16;
typedef _Float16 f16x2 __attribute__((ext_vector_type(2)));
typedef _Float16 f16x4 __attribute__((ext_vector_type(4)));
typedef _Float16 f16x8 __attribute__((ext_vector_type(8)));
typedef float f32x4 __attribute__((ext_vector_type(4)));
typedef unsigned int u32x4 __attribute__((ext_vector_type(4)));

#define MFMA16 __builtin_amdgcn_mfma_f32_16x16x32_bf16
#define MFMA16H __builtin_amdgcn_mfma_f32_16x16x32_f16

// async 16B/lane global->LDS copy; HW scatters lane i to lds + i*16 (wave-uniform base)
__device__ __forceinline__ void async16(void* lds, const void* g) {
    __builtin_amdgcn_global_load_lds((const __attribute__((address_space(1))) unsigned int*)g,
                                     (__attribute__((address_space(3))) unsigned int*)lds, 16, 0, 0);
}

// packed f32x2 -> f16x2 (cvt_pkrtz returns __fp16-based vector; bit-cast to _Float16-based)
__device__ __forceinline__ f16x2 pkrtz(float a, float b) {
    return __builtin_bit_cast(f16x2, __builtin_amdgcn_cvt_pkrtz(a, b));
}

__device__ __forceinline__ float fdot2h(f16x2 a, f16x2 b, float c) {
#if __has_builtin(__builtin_amdgcn_fdot2)
    return __builtin_amdgcn_fdot2(a, b, c, false);
#else
    return c + (float)a[0] * (float)b[0] + (float)a[1] * (float)b[1];
#endif
}

// ---------------------------------------------------------------------------
// K0 "prep": weight cvt (blocks 0..255) + three activation transposes
// (s3: 256..767, s4: 768..1023, s5: 1024..1151).
__global__ __launch_bounds__(256) void k_prep(const float* __restrict__ qw, const float* __restrict__ kw,
                                              const float* __restrict__ vw, const float* __restrict__ ow,
                                              bf16* __restrict__ Wb,
                                              const float* __restrict__ s3, const float* __restrict__ s4,
                                              const float* __restrict__ s5,
                                              bf16* __restrict__ s3t, bf16* __restrict__ s45t) {
    __shared__ float T[64][65];
    int bx = blockIdx.x, t = threadIdx.x;
    if (bx < 256) {
        int tt = bx * 256 + t;
        const float* srcs[4] = {qw, kw, vw, ow};
        int which = tt >> 14;
        int idx = (tt & 16383) * 4;
        f32x4 v = *(const f32x4*)(srcs[which] + idx);
        bf16x4 o;
        o[0] = (bf16)v[0]; o[1] = (bf16)v[1]; o[2] = (bf16)v[2]; o[3] = (bf16)v[3];
        *(bf16x4*)(Wb + (size_t)which * 65536 + idx) = o;
        return;
    }
    const float* src; bf16* dst; int N, dstRows, rowOff, x, y, z;
    if (bx < 768)       { int i = bx - 256;  src = s3; dst = s3t;  N = 4096; dstRows = 4096; rowOff = 0;    x = i & 63; y = (i >> 6) & 3; z = i >> 8; }
    else if (bx < 1024) { int i = bx - 768;  src = s4; dst = s45t; N = 2048; dstRows = 3072; rowOff = 0;    x = i & 31; y = (i >> 5) & 3; z = i >> 7; }
    else                { int i = bx - 1024; src = s5; dst = s45t; N = 1024; dstRows = 3072; rowOff = 2048; x = i & 15; y = (i >> 4) & 3; z = i >> 6; }
    int c0 = y * 64, n0 = x * 64, b = z;
    const float* s = src + ((size_t)b * 256 + c0) * N + n0;
#pragma unroll
    for (int i = 0; i < 4; i++) {
        int flat = i * 256 + t;
        int row = flat >> 4;
        int col = (flat & 15) * 4;
        f32x4 v = *(const f32x4*)(s + (size_t)row * N + col);
        T[row][col + 0] = v[0]; T[row][col + 1] = v[1];
        T[row][col + 2] = v[2]; T[row][col + 3] = v[3];
    }
    __syncthreads();
#pragma unroll
    for (int i = 0; i < 4; i++) {
        int flat = i * 256 + t;
        int nrow = flat >> 4;
        int c4 = (flat & 15) * 4;
        bf16x4 o;
        o[0] = (bf16)T[c4 + 0][nrow]; o[1] = (bf16)T[c4 + 1][nrow];
        o[2] = (bf16)T[c4 + 2][nrow]; o[3] = (bf16)T[c4 + 3][nrow];
        *(bf16x4*)(dst + ((size_t)(b * dstRows + rowOff + n0 + nrow)) * 256 + c0 + c4) = o;
    }
}

// ---------------------------------------------------------------------------
// K1 "qkv": Q blocks 0..511 (mode 0), K 512..895 (mode 1), V 896..1279 (mode 2).
// mode 0: Q bf16 [bh][n][32], pre-scaled by 32^-.5*log2e.
// mode 1: K bf16 [bh][n'][32], n' row-permuted within 32-blocks.
// mode 2: V f16 [bh][32 d][3072 kn], kn permuted per 64-chunk by d-keyed XOR;
// R15: operand-swapped MFMA (D^T) -> 4x f16x4 stores instead of 16 scalar.
// R13: counted-vmcnt pipeline (raw s_barrier + vmcnt(2)).
__global__ __launch_bounds__(256) void k_qkv(const bf16* __restrict__ Wb,
                                             const bf16* __restrict__ s3t, const bf16* __restrict__ s45t,
                                             const float* __restrict__ qb, const float* __restrict__ kb,
                                             const float* __restrict__ vb,
                                             bf16* __restrict__ Qb, bf16* __restrict__ Kb,
                                             f16* __restrict__ Vtb, float qscale) {
    int i = blockIdx.x;
    int mode, n0, m0, b, Nrows;
    const bf16 *A, *Bt; const float* bias; float oscale = 1.0f;
    if (i < 512) {
        mode = 0; A = Wb; Bt = s3t; bias = qb; Nrows = 4096; oscale = qscale;
        n0 = (i & 63) * 64; m0 = ((i >> 6) & 3) * 64; b = i >> 8;
    } else if (i < 896) {
        unsigned j = i - 512;
        mode = 1; A = Wb + 65536; Bt = s45t; bias = kb; Nrows = 3072;
        n0 = (j % 48u) * 64; unsigned rr = j / 48u; m0 = (rr & 3) * 64; b = rr >> 2;
    } else {
        unsigned j = i - 896;
        mode = 2; A = Wb + 131072; Bt = s45t; bias = vb; Nrows = 3072;
        n0 = (j % 48u) * 64; unsigned rr = j / 48u; m0 = (rr & 3) * 64; b = rr >> 2;
    }
    __shared__ __align__(16) bf16 As[2][64 * 32];
    __shared__ __align__(16) bf16 Bs[2][64 * 32];
    int t = threadIdx.x;
    int w = t >> 6, lane = t & 63;
    int lrow = lane & 15, lk = lane >> 4;
    f32x4 acc[4] = {};
    const bf16* Ag = A + (size_t)(m0 + w * 16 + (lane >> 2)) * 256 + (lane & 3) * 8;
    const bf16* Bg = Bt + ((size_t)b * Nrows + n0 + w * 16 + (lane >> 2)) * 256 + (lane & 3) * 8;
    async16(&As[0][w * 512], Ag);
    async16(&Bs[0][w * 512], Bg);
    async16(&As[1][w * 512], Ag + 32);
    async16(&Bs[1][w * 512], Bg + 32);
    for (int s8 = 0; s8 < 8; ++s8) {
        int buf = s8 & 1;
        if (s8 < 7) asm volatile("s_waitcnt vmcnt(2)" ::: "memory");
        else        asm volatile("s_waitcnt vmcnt(0)" ::: "memory");
        __builtin_amdgcn_s_barrier();
        __builtin_amdgcn_sched_barrier(0);
        bf16x8 af = *(const bf16x8*)(&As[buf][(w * 16 + lrow) * 32 + lk * 8]);
#pragma unroll
        for (int ct = 0; ct < 4; ct++) {
            bf16x8 bfr = *(const bf16x8*)(&Bs[buf][(ct * 16 + lrow) * 32 + lk * 8]);
            if (mode == 2) acc[ct] = MFMA16(bfr, af, acc[ct], 0, 0, 0);   // D^T: rows=n, cols=o
            else           acc[ct] = MFMA16(af, bfr, acc[ct], 0, 0, 0);   // rows=o, cols=n
        }
        __builtin_amdgcn_s_barrier();
        if (s8 < 6) {
            async16(&As[buf][w * 512], Ag + (s8 + 2) * 32);
            async16(&Bs[buf][w * 512], Bg + (s8 + 2) * 32);
        }
    }
    // C/D layout: col = lane&15, row = (lane>>4)*4 + reg  [verified m89/m91]
    if (mode == 2) {
        // lane: o = m0 + w*16 + lrow (fixed), n = n0 + ct*16 + lk*4 + j (consecutive)
        int o = m0 + w * 16 + lrow;
        int head = o >> 5;
        int dd = o & 31;
        float bs = bias[o];
        int key = dd & 7;
        f16* vrow = Vtb + ((size_t)(b * 8 + head) * 32 + dd) * 3072;
#pragma unroll
        for (int ct = 0; ct < 4; ct++) {
            int g = ct * 2 + (lk >> 1);                       // 8-elem granule of n&63
            int col = n0 + ((g ^ key) << 3) + (lk & 1) * 4;   // XOR-permuted position
            f16x4 pv;
#pragma unroll
            for (int j = 0; j < 4; j++) pv[j] = (f16)(acc[ct][j] + bs);
            *(f16x4*)(vrow + col) = pv;
        }
    } else {
        int o0 = m0 + w * 16 + lk * 4;
        f32x4 b4 = *(const f32x4*)(bias + o0);
        int head = o0 >> 5;
#pragma unroll
        for (int ct = 0; ct < 4; ct++) {
            int n = n0 + ct * 16 + lrow;
            if (mode == 0) {
                int dd = o0 & 31;
                bf16x4 pv;
#pragma unroll
                for (int j = 0; j < 4; j++) pv[j] = (bf16)((acc[ct][j] + b4[j]) * oscale);
                *(bf16x4*)(Qb + ((size_t)(b * 8 + head) * 4096 + n) * 32 + dd) = pv;
            } else {
                int dd = o0 & 31;
                int u = n & 31;
                int np = (n & ~31) | (((u >> 2) & 1) << 4) | ((u >> 3) << 2) | (u & 3);
                bf16x4 pv;
#pragma unroll
                for (int j = 0; j < 4; j++) pv[j] = (bf16)(acc[ct][j] + b4[j]);
                *(bf16x4*)(Kb + ((size_t)(b * 8 + head) * 3072 + np) * 32 + dd) = pv;
            }
        }
    }
}

// ---------------------------------------------------------------------------
// K2: attention (R15 config restored — R17's (256,6) cap spilled accO to
// scratch: 288MB writes, 3x regression; (256,4) with 64 VGPR is the proven
// operating point). S^T = K·Q^T; exp2'd C/D regs form K=32 f16 B-operand for
// PV (V^T as A): out^T[d][q] += V^T·P^T.
// Per-wave q-tile 64 (4 q-groups): each kf/vf LDS read feeds 16 MFMAs.
// KVBLK=128, 6 iters, counted-vmcnt dbuf; split-kn=4; XCD swizzle (id&63).
__global__ __launch_bounds__(256, 4) void k_attn(const bf16* __restrict__ Q, const bf16* __restrict__ K,
                                                 const f16* __restrict__ Vt,
                                                 f16* __restrict__ Opart, float* __restrict__ Lsum) {
    int id = blockIdx.x;
    int bh = id & 15;
    int sp = (id >> 4) & 3;
    int q0 = (id >> 6) * 256;
    int kn0 = sp * 768;
    int t = threadIdx.x, w = t >> 6, lane = t & 63;
    int lrow = lane & 15, lk = lane >> 4;
    __shared__ __align__(16) char smem[32768];
    bf16* Ks = (bf16*)smem;           // [2][128*32] bf16 (buf stride 4096 elems)
    f16* Vs = (f16*)(smem + 16384);   // [2][2 sub][32*64] f16 (buf stride 4096, sub 2048)
    f16* Tq = (f16*)smem;             // epilogue: per-wave 32 x 66 (aliases Ks)
    const bf16* kbase = K + (size_t)bh * 3072 * 32;
    const f16* vbase = Vt + (size_t)bh * 32 * 3072;
    const bf16* kg = kbase + (size_t)(kn0 + w * 16 + (lane >> 2)) * 32 + (lane & 3) * 8;
    const f16* vg = vbase + (size_t)(w * 8 + (lane >> 3)) * 3072 + kn0 + (lane & 7) * 8;
    // Q as B-operand: B[k=d=lk*8+j][n=q=lrow], one frag per 16-q group
    bf16x8 aq[4];
#pragma unroll
    for (int qg = 0; qg < 4; ++qg)
        aq[qg] = *(const bf16x8*)(Q + ((size_t)bh * 4096 + q0 + w * 64 + qg * 16 + lrow) * 32 + lk * 8);
    f32x4 accO[4][2] = {};   // [q-group][d-half], out^T: row=d_local, col=q
    float lsum[4] = {0.f, 0.f, 0.f, 0.f};
    f32x4 zero = {};
    f16x2 one2; one2[0] = (f16)1.f; one2[1] = (f16)1.f;
    int vkey = lrow & 7;     // V image XOR key = d&7 (same for both d-halves)
    // prologue: stage tiles 0 and 1 (4 loads each)
    async16(Ks + w * 512, kg);
    async16(Ks + 2048 + w * 512, kg + 64 * 32);
    async16(Vs + w * 512, vg);
    async16(Vs + 2048 + w * 512, vg + 64);
    {
        const bf16* kn_ = kg + 128 * 32;
        const f16* vn_ = vg + 128;
        async16(Ks + 4096 + w * 512, kn_);
        async16(Ks + 4096 + 2048 + w * 512, kn_ + 64 * 32);
        async16(Vs + 4096 + w * 512, vn_);
        async16(Vs + 4096 + 2048 + w * 512, vn_ + 64);
    }
    for (int c = 0; c < 6; ++c) {
        int buf = c & 1;
        // wait for THIS tile's 4 loads; next tile's 4 stay in flight
        if (c < 5) asm volatile("s_waitcnt vmcnt(4)" ::: "memory");
        else       asm volatile("s_waitcnt vmcnt(0)" ::: "memory");
        __builtin_amdgcn_s_barrier();
        __builtin_amdgcn_sched_barrier(0);
        const bf16* ksb = Ks + buf * 4096;
        const f16* vsb0 = Vs + buf * 4096;
#pragma unroll
        for (int p = 0; p < 4; ++p) {   // four 32-kn chunks
            bf16x8 kf0 = *(const bf16x8*)(ksb + (p * 32 + lrow) * 32 + lk * 8);
            bf16x8 kf1 = *(const bf16x8*)(ksb + (p * 32 + 16 + lrow) * 32 + lk * 8);
            const f16* vsb = vsb0 + (p >> 1) * 2048;
            int gran = (((p & 1) << 2) | lk) ^ vkey;
            f16x8 vf0 = *(const f16x8*)(vsb + lrow * 64 + (gran << 3));
            f16x8 vf1 = *(const f16x8*)(vsb + (16 + lrow) * 64 + (gran << 3));
#pragma unroll
            for (int qg = 0; qg < 4; ++qg) {   // kf/vf shared across 4 qg
                f32x4 s0 = MFMA16(kf0, aq[qg], zero, 0, 0, 0);
                f32x4 s1 = MFMA16(kf1, aq[qg], zero, 0, 0, 0);
                f16x2 h0 = pkrtz(__builtin_amdgcn_exp2f(s0[0]), __builtin_amdgcn_exp2f(s0[1]));
                f16x2 h1 = pkrtz(__builtin_amdgcn_exp2f(s0[2]), __builtin_amdgcn_exp2f(s0[3]));
                f16x2 h2 = pkrtz(__builtin_amdgcn_exp2f(s1[0]), __builtin_amdgcn_exp2f(s1[1]));
                f16x2 h3 = pkrtz(__builtin_amdgcn_exp2f(s1[2]), __builtin_amdgcn_exp2f(s1[3]));
                f16x8 pk;
                pk[0] = h0[0]; pk[1] = h0[1]; pk[2] = h1[0]; pk[3] = h1[1];
                pk[4] = h2[0]; pk[5] = h2[1]; pk[6] = h3[0]; pk[7] = h3[1];
                lsum[qg] = fdot2h(h0, one2, lsum[qg]);
                lsum[qg] = fdot2h(h1, one2, lsum[qg]);
                lsum[qg] = fdot2h(h2, one2, lsum[qg]);
                lsum[qg] = fdot2h(h3, one2, lsum[qg]);
                accO[qg][0] = MFMA16H(vf0, pk, accO[qg][0], 0, 0, 0);
                accO[qg][1] = MFMA16H(vf1, pk, accO[qg][1], 0, 0, 0);
            }
        }
        // all LDS reads consumed above; separate read-phase from overwrite
        __builtin_amdgcn_s_barrier();
        if (c < 4) {
            const bf16* kn_ = kg + (size_t)(c + 2) * 128 * 32;
            const f16* vn_ = vg + (c + 2) * 128;
            async16(Ks + buf * 4096 + w * 512, kn_);
            async16(Ks + buf * 4096 + 2048 + w * 512, kn_ + 64 * 32);
            async16(Vs + buf * 4096 + w * 512, vn_);
            async16(Vs + buf * 4096 + 2048 + w * 512, vn_ + 64);
        }
    }
    // L: reduce per-lane partials over lk (lanes lrow, lrow+16, +32, +48)
    int sb = sp * 16 + bh;
#pragma unroll
    for (int qg = 0; qg < 4; ++qg) {
        lsum[qg] += __shfl_xor(lsum[qg], 16, 64);
        lsum[qg] += __shfl_xor(lsum[qg], 32, 64);
    }
    if (lane < 16) {
#pragma unroll
        for (int qg = 0; qg < 4; ++qg)
            Lsum[(size_t)sb * 4096 + q0 + w * 64 + qg * 16 + lane] = lsum[qg];
    }
    // O epilogue: same-wave LDS transpose [d][q] -> coalesced [q][d] f16 stores
    f16* tw = Tq + w * 2112;   // 32 d-rows x 66 (pad)
#pragma unroll
    for (int qg = 0; qg < 4; ++qg)
#pragma unroll
        for (int dh = 0; dh < 2; ++dh)
#pragma unroll
            for (int i = 0; i < 4; ++i)
                tw[(dh * 16 + lk * 4 + i) * 66 + qg * 16 + lrow] = (f16)accO[qg][dh][i];
    int q4 = (lane & 15) * 4, dgrp = (lane >> 4) * 8;
#pragma unroll
    for (int qq = 0; qq < 4; ++qq) {
        f16x8 ov;
#pragma unroll
        for (int dj = 0; dj < 8; ++dj) ov[dj] = tw[(dgrp + dj) * 66 + q4 + qq];
        *(f16x8*)(Opart + ((size_t)sb * 4096 + q0 + w * 64 + q4 + qq) * 32 + dgrp) = ov;
    }
}

// ---------------------------------------------------------------------------
// K3 "oln": o-projection + split-kn combine + bias + residual + LayerNorm +
// output transpose. R18: 16 q x 256 c blocks (grid 512 = 2 blocks/CU). With
// the hoisted combine + async16 A-staging (R15), the extra A re-reads are
// L2-resident (one shared 128KB weight panel), so doubling block count buys
// TLP at ~zero HBM cost. (R10's regression predates hoist/async — retest.)
__global__ __launch_bounds__(256) void k_oln(const bf16* __restrict__ A, const f16* __restrict__ Opart,
                                             const float* __restrict__ Ls, const float* __restrict__ bias,
                                             const bf16* __restrict__ s3t,
                                             const float* __restrict__ lnw, const float* __restrict__ lnb,
                                             float* __restrict__ out) {
    int i = blockIdx.x;
    int b = i >> 8, n0 = (i & 255) * 16;
    __shared__ __align__(16) char smem[41728];
    bf16* As = (bf16*)smem;                 // [2][256*32] bf16 = 32768 B (async16 dest, linear)
    bf16* Bs = (bf16*)(smem + 32768);       // 16 x 264 bf16 = 8448 B (GEMM phase)
    float* T = (float*)smem;                // 16 x 257 f32 = 16448 B (LN phase, aliases As)
    float* ps = (float*)(smem + 41216);     // [4 w][16 n]
    float* pq = (float*)(smem + 41472);     // [4 w][16 n] (41728 total)
    float* mu_s = (float*)(smem + 16448);   // [16] (aliases As tail, dead by then)
    float* rs_s = (float*)(smem + 16512);   // [16]
    int t = threadIdx.x, w = t >> 6, lane = t & 63;
    int lrow = lane & 15, lk = lane >> 4;
    f32x4 acc[4] = {};                      // [mt: c-64-block], 16-q tile
    const size_t SPS = (size_t)16 * 4096 * 32;   // Opart sp stride (elems)
    // A staging: granule f = (w*4+s)*64 + lane; row = f>>2, col-granule = f&3.
#define STAGE_A(buf_, kc_)                                                              \
    {                                                                                   \
        _Pragma("unroll")                                                               \
        for (int s_ = 0; s_ < 4; ++s_) {                                                \
            int f_ = (w * 4 + s_) * 64 + lane;                                          \
            async16(As + (buf_) * 8192 + f_ * 8,                                        \
                    A + (size_t)(f_ >> 2) * 256 + (kc_) + (f_ & 3) * 8);                \
        }                                                                               \
    }
    STAGE_A(0, 0)
    STAGE_A(1, 32)
    // hoisted combine: B[16 q][256 c] = (sum_sp Opart) / (sum_sp Ls)
    {
        int rB = t >> 4;                // 0..15 (q row)
        int q = n0 + rB;
        int c0g = (t & 15) * 4;         // 0..60
        float l = 0.f;
#pragma unroll
        for (int sp = 0; sp < 4; ++sp) l += Ls[(size_t)(sp * 16 + b * 8) * 4096 + q];
        // NOTE: L depends only on (b,q) via per-head rows; recompute per cg below
#pragma unroll
        for (int cc = 0; cc < 4; ++cc) {
            int c = cc * 64 + c0g;
            int bh = b * 8 + (c >> 5);
            float lh = 0.f;
#pragma unroll
            for (int sp = 0; sp < 4; ++sp) lh += Ls[(size_t)(sp * 16 + bh) * 4096 + q];
            float rl = 1.0f / lh;
            const f16* obp = Opart + ((size_t)bh * 4096 + q) * 32 + (c & 31);
            f32x4 sv = {};
#pragma unroll
            for (int sp = 0; sp < 4; ++sp) {
                f16x4 av = *(const f16x4*)(obp + sp * SPS);
#pragma unroll
                for (int j = 0; j < 4; ++j) sv[j] += (float)av[j];
            }
            bf16x4 bb;
#pragma unroll
            for (int j = 0; j < 4; ++j) bb[j] = (bf16)(sv[j] * rl);
            *(bf16x4*)(Bs + rB * 264 + c) = bb;
        }
        (void)l;
    }
    asm volatile("s_waitcnt lgkmcnt(0)" ::: "memory");   // Bs writes drained pre-barrier
    for (int s8 = 0; s8 < 8; ++s8) {
        int buf = s8 & 1;
        int kc = s8 * 32;
        if (s8 < 7) asm volatile("s_waitcnt vmcnt(4)" ::: "memory");
        else        asm volatile("s_waitcnt vmcnt(0)" ::: "memory");
        __builtin_amdgcn_s_barrier();
        __builtin_amdgcn_sched_barrier(0);
        bf16x8 bfr = *(const bf16x8*)(Bs + lrow * 264 + kc + lk * 8);
#pragma unroll
        for (int mt = 0; mt < 4; ++mt) {
            bf16x8 af = *(const bf16x8*)(As + buf * 8192 + (mt * 64 + w * 16 + lrow) * 32 + lk * 8);
            acc[mt] = MFMA16(af, bfr, acc[mt], 0, 0, 0);
        }
        __builtin_amdgcn_s_barrier();
        if (s8 < 6) STAGE_A(buf, (s8 + 2) * 32)
    }
#undef STAGE_A
    // epilogue: bias + residual; write raw values to T; accumulate LN stats
    float wsum = 0.f, wsq = 0.f;
    int n = lrow;
#pragma unroll
    for (int mt = 0; mt < 4; ++mt) {
        int c0 = mt * 64 + w * 16 + lk * 4;
        f32x4 b4 = *(const f32x4*)(bias + c0);
        bf16x4 rv = *(const bf16x4*)(s3t + ((size_t)b * 4096 + n0 + n) * 256 + c0);
#pragma unroll
        for (int j = 0; j < 4; ++j) {
            float v = acc[mt][j] + b4[j] + (float)rv[j];
            T[n * 257 + c0 + j] = v;
            wsum += v;
            wsq += v * v;
        }
    }
    wsum += __shfl_xor(wsum, 16, 64);
    wsum += __shfl_xor(wsum, 32, 64);
    wsq += __shfl_xor(wsq, 16, 64);
    wsq += __shfl_xor(wsq, 32, 64);
    if (lk == 0) {
        ps[w * 16 + lrow] = wsum;
        pq[w * 16 + lrow] = wsq;
    }
    __syncthreads();
    if (t < 16) {
        float S = ps[t] + ps[16 + t] + ps[32 + t] + ps[48 + t];
        float Q2 = pq[t] + pq[16 + t] + pq[32 + t] + pq[48 + t];
        float m = S * (1.0f / 256.0f);
        mu_s[t] = m;
        rs_s[t] = rsqrtf(Q2 * (1.0f / 256.0f) - m * m + 1e-5f);
    }
    __syncthreads();
    // write out[b][c][n0..n0+15], coalesced along n
    int cb = t >> 2, n4 = (t & 3) * 4;
#pragma unroll
    for (int cc4 = 0; cc4 < 4; ++cc4) {
        int c = cb + cc4 * 64;
        float wv = lnw[c], bv = lnb[c];
        f32x4 o;
#pragma unroll
        for (int k2 = 0; k2 < 4; ++k2)
            o[k2] = (T[(n4 + k2) * 257 + c] - mu_s[n4 + k2]) * rs_s[n4 + k2] * wv + bv;
        *(f32x4*)(out + ((size_t)b * 256 + c) * 4096 + n0 + n4) = o;
    }
}

// ---------------------------------------------------------------------------
extern "C" void kernel_launch(void* const* d_in, const int* in_sizes, int n_in,
                              void* d_out, int out_size, void* d_ws, size_t ws_size,
                              hipStream_t stream) {
    const float* s3  = (const float*)d_in[0];
    const float* s4  = (const float*)d_in[1];
    const float* s5  = (const float*)d_in[2];
    const float* qw  = (const float*)d_in[3];
    const float* qb  = (const float*)d_in[4];
    const float* kw  = (const float*)d_in[5];
    const float* kb  = (const float*)d_in[6];
    const float* vw  = (const float*)d_in[7];
    const float* vb  = (const float*)d_in[8];
    const float* ow  = (const float*)d_in[9];
    const float* ob  = (const float*)d_in[10];
    const float* lnw = (const float*)d_in[11];
    const float* lnb = (const float*)d_in[12];
    float* out = (float*)d_out;
    char* ws = (char*)d_ws;

    // workspace layout (~34.5 MB peak):
    bf16* Wb    = (bf16*)(ws);                          // 512 KB @ 0
    bf16* s3t   = (bf16*)(ws + (512ull << 10));         // 4 MB  @ 0.5 MB (live till k_oln)
    bf16* s45t  = (bf16*)(ws + (4608ull << 10));        // 3 MB  @ 4.5 MB
    bf16* Qb    = (bf16*)(ws + (7680ull << 10));        // 4 MB  @ 7.5 MB
    bf16* Kb    = Qb + (2ull * 8 * 4096 * 32);          // 3 MB  @ 11.5 MB
    f16*  Vtb   = (f16*)(Kb + (2ull * 8 * 3072 * 32));  // 3 MB  @ 14.5 MB
    f16*  Opart = (f16*)(ws + (17920ull << 10));        // 16 MB @ 17.5 MB (f16 [4sp][16bh][4096q][32d])
    float* Lsum = (float*)(ws + (34304ull << 10));      // 1 MB  @ 33.5 MB

    const float qscale = 0.17677669529663688f * 1.4426950408889634f;  // 32^-0.5 * log2(e)

    k_prep<<<1152, 256, 0, stream>>>(qw, kw, vw, ow, Wb, s3, s4, s5, s3t, s45t);
    k_qkv<<<1280, 256, 0, stream>>>(Wb, s3t, s45t, qb, kb, vb, Qb, Kb, Vtb, qscale);
    k_attn<<<1024, 256, 0, stream>>>(Qb, Kb, Vtb, Opart, Lsum);
    k_oln<<<512, 256, 0, stream>>>(Wb + 196608, Opart, Lsum, ob, s3t, lnw, lnb, out);
}

// Round 10
// 138.426 us; speedup vs baseline: 1.6063x; 1.0273x over previous
//
#include <hip/hip_runtime.h>

typedef __bf16 bf16;
typedef __bf16 bf16x4 __attribute__((ext_vector_type(4)));
typedef __bf16 bf16x8 __attribute__((ext_vector_type(8)));
typedef _Float16 f16;
typedef _Float16 f16x2 __attribute__((ext_vector_type(2)));
typedef _Float16 f16x4 __attribute__((ext_vector_type(4)));
typedef _Float16 f16x8 __attribute__((ext_vector_type(8)));
typedef float f32x4 __attribute__((ext_vector_type(4)));
typedef unsigned int u32x4 __attribute__((ext_vector_type(4)));

#define MFMA16 __builtin_amdgcn_mfma_f32_16x16x32_bf16
#define MFMA16H __builtin_amdgcn_mfma_f32_16x16x32_f16

// async 16B/lane global->LDS copy; HW scatters lane i to lds + i*16 (wave-uniform base)
__device__ __forceinline__ void async16(void* lds, const void* g) {
    __builtin_amdgcn_global_load_lds((const __attribute__((address_space(1))) unsigned int*)g,
                                     (__attribute__((address_space(3))) unsigned int*)lds, 16, 0, 0);
}

// packed f32x2 -> f16x2 (cvt_pkrtz returns __fp16-based vector; bit-cast to _Float16-based)
__device__ __forceinline__ f16x2 pkrtz(float a, float b) {
    return __builtin_bit_cast(f16x2, __builtin_amdgcn_cvt_pkrtz(a, b));
}

// ---------------------------------------------------------------------------
// K0 "prep": weight cvt (blocks 0..255) + three activation transposes
// (s3: 256..767, s4: 768..1023, s5: 1024..1151).
__global__ __launch_bounds__(256) void k_prep(const float* __restrict__ qw, const float* __restrict__ kw,
                                              const float* __restrict__ vw, const float* __restrict__ ow,
                                              bf16* __restrict__ Wb,
                                              const float* __restrict__ s3, const float* __restrict__ s4,
                                              const float* __restrict__ s5,
                                              bf16* __restrict__ s3t, bf16* __restrict__ s45t) {
    __shared__ float T[64][65];
    int bx = blockIdx.x, t = threadIdx.x;
    if (bx < 256) {
        int tt = bx * 256 + t;
        const float* srcs[4] = {qw, kw, vw, ow};
        int which = tt >> 14;
        int idx = (tt & 16383) * 4;
        f32x4 v = *(const f32x4*)(srcs[which] + idx);
        bf16x4 o;
        o[0] = (bf16)v[0]; o[1] = (bf16)v[1]; o[2] = (bf16)v[2]; o[3] = (bf16)v[3];
        *(bf16x4*)(Wb + (size_t)which * 65536 + idx) = o;
        return;
    }
    const float* src; bf16* dst; int N, dstRows, rowOff, x, y, z;
    if (bx < 768)       { int i = bx - 256;  src = s3; dst = s3t;  N = 4096; dstRows = 4096; rowOff = 0;    x = i & 63; y = (i >> 6) & 3; z = i >> 8; }
    else if (bx < 1024) { int i = bx - 768;  src = s4; dst = s45t; N = 2048; dstRows = 3072; rowOff = 0;    x = i & 31; y = (i >> 5) & 3; z = i >> 7; }
    else                { int i = bx - 1024; src = s5; dst = s45t; N = 1024; dstRows = 3072; rowOff = 2048; x = i & 15; y = (i >> 4) & 3; z = i >> 6; }
    int c0 = y * 64, n0 = x * 64, b = z;
    const float* s = src + ((size_t)b * 256 + c0) * N + n0;
#pragma unroll
    for (int i = 0; i < 4; i++) {
        int flat = i * 256 + t;
        int row = flat >> 4;
        int col = (flat & 15) * 4;
        f32x4 v = *(const f32x4*)(s + (size_t)row * N + col);
        T[row][col + 0] = v[0]; T[row][col + 1] = v[1];
        T[row][col + 2] = v[2]; T[row][col + 3] = v[3];
    }
    __syncthreads();
#pragma unroll
    for (int i = 0; i < 4; i++) {
        int flat = i * 256 + t;
        int nrow = flat >> 4;
        int c4 = (flat & 15) * 4;
        bf16x4 o;
        o[0] = (bf16)T[c4 + 0][nrow]; o[1] = (bf16)T[c4 + 1][nrow];
        o[2] = (bf16)T[c4 + 2][nrow]; o[3] = (bf16)T[c4 + 3][nrow];
        *(bf16x4*)(dst + ((size_t)(b * dstRows + rowOff + n0 + nrow)) * 256 + c0 + c4) = o;
    }
}

// ---------------------------------------------------------------------------
// K1 "qkv": Q blocks 0..511 (mode 0), K 512..895 (mode 1), V 896..1279 (mode 2).
// mode 0: Q bf16 [bh][n][32], pre-scaled by 32^-.5*log2e.
// mode 1: K bf16 [bh][n'][32], n' row-permuted within 32-blocks.
// mode 2: V f16 [bh][32 d][3072 kn], kn permuted per 64-chunk by d-keyed XOR;
// R15: operand-swapped MFMA (D^T) -> 4x f16x4 stores instead of 16 scalar.
// R13: counted-vmcnt pipeline (raw s_barrier + vmcnt(2)).
__global__ __launch_bounds__(256) void k_qkv(const bf16* __restrict__ Wb,
                                             const bf16* __restrict__ s3t, const bf16* __restrict__ s45t,
                                             const float* __restrict__ qb, const float* __restrict__ kb,
                                             const float* __restrict__ vb,
                                             bf16* __restrict__ Qb, bf16* __restrict__ Kb,
                                             f16* __restrict__ Vtb, float qscale) {
    int i = blockIdx.x;
    int mode, n0, m0, b, Nrows;
    const bf16 *A, *Bt; const float* bias; float oscale = 1.0f;
    if (i < 512) {
        mode = 0; A = Wb; Bt = s3t; bias = qb; Nrows = 4096; oscale = qscale;
        n0 = (i & 63) * 64; m0 = ((i >> 6) & 3) * 64; b = i >> 8;
    } else if (i < 896) {
        unsigned j = i - 512;
        mode = 1; A = Wb + 65536; Bt = s45t; bias = kb; Nrows = 3072;
        n0 = (j % 48u) * 64; unsigned rr = j / 48u; m0 = (rr & 3) * 64; b = rr >> 2;
    } else {
        unsigned j = i - 896;
        mode = 2; A = Wb + 131072; Bt = s45t; bias = vb; Nrows = 3072;
        n0 = (j % 48u) * 64; unsigned rr = j / 48u; m0 = (rr & 3) * 64; b = rr >> 2;
    }
    __shared__ __align__(16) bf16 As[2][64 * 32];
    __shared__ __align__(16) bf16 Bs[2][64 * 32];
    int t = threadIdx.x;
    int w = t >> 6, lane = t & 63;
    int lrow = lane & 15, lk = lane >> 4;
    f32x4 acc[4] = {};
    const bf16* Ag = A + (size_t)(m0 + w * 16 + (lane >> 2)) * 256 + (lane & 3) * 8;
    const bf16* Bg = Bt + ((size_t)b * Nrows + n0 + w * 16 + (lane >> 2)) * 256 + (lane & 3) * 8;
    async16(&As[0][w * 512], Ag);
    async16(&Bs[0][w * 512], Bg);
    async16(&As[1][w * 512], Ag + 32);
    async16(&Bs[1][w * 512], Bg + 32);
    for (int s8 = 0; s8 < 8; ++s8) {
        int buf = s8 & 1;
        if (s8 < 7) asm volatile("s_waitcnt vmcnt(2)" ::: "memory");
        else        asm volatile("s_waitcnt vmcnt(0)" ::: "memory");
        __builtin_amdgcn_s_barrier();
        __builtin_amdgcn_sched_barrier(0);
        bf16x8 af = *(const bf16x8*)(&As[buf][(w * 16 + lrow) * 32 + lk * 8]);
#pragma unroll
        for (int ct = 0; ct < 4; ct++) {
            bf16x8 bfr = *(const bf16x8*)(&Bs[buf][(ct * 16 + lrow) * 32 + lk * 8]);
            if (mode == 2) acc[ct] = MFMA16(bfr, af, acc[ct], 0, 0, 0);   // D^T: rows=n, cols=o
            else           acc[ct] = MFMA16(af, bfr, acc[ct], 0, 0, 0);   // rows=o, cols=n
        }
        __builtin_amdgcn_s_barrier();
        if (s8 < 6) {
            async16(&As[buf][w * 512], Ag + (s8 + 2) * 32);
            async16(&Bs[buf][w * 512], Bg + (s8 + 2) * 32);
        }
    }
    // C/D layout: col = lane&15, row = (lane>>4)*4 + reg  [verified m89/m91]
    if (mode == 2) {
        // lane: o = m0 + w*16 + lrow (fixed), n = n0 + ct*16 + lk*4 + j (consecutive)
        int o = m0 + w * 16 + lrow;
        int head = o >> 5;
        int dd = o & 31;
        float bs = bias[o];
        int key = dd & 7;
        f16* vrow = Vtb + ((size_t)(b * 8 + head) * 32 + dd) * 3072;
#pragma unroll
        for (int ct = 0; ct < 4; ct++) {
            int g = ct * 2 + (lk >> 1);                       // 8-elem granule of n&63
            int col = n0 + ((g ^ key) << 3) + (lk & 1) * 4;   // XOR-permuted position
            f16x4 pv;
#pragma unroll
            for (int j = 0; j < 4; j++) pv[j] = (f16)(acc[ct][j] + bs);
            *(f16x4*)(vrow + col) = pv;
        }
    } else {
        int o0 = m0 + w * 16 + lk * 4;
        f32x4 b4 = *(const f32x4*)(bias + o0);
        int head = o0 >> 5;
#pragma unroll
        for (int ct = 0; ct < 4; ct++) {
            int n = n0 + ct * 16 + lrow;
            if (mode == 0) {
                int dd = o0 & 31;
                bf16x4 pv;
#pragma unroll
                for (int j = 0; j < 4; j++) pv[j] = (bf16)((acc[ct][j] + b4[j]) * oscale);
                *(bf16x4*)(Qb + ((size_t)(b * 8 + head) * 4096 + n) * 32 + dd) = pv;
            } else {
                int dd = o0 & 31;
                int u = n & 31;
                int np = (n & ~31) | (((u >> 2) & 1) << 4) | ((u >> 3) << 2) | (u & 3);
                bf16x4 pv;
#pragma unroll
                for (int j = 0; j < 4; j++) pv[j] = (bf16)(acc[ct][j] + b4[j]);
                *(bf16x4*)(Kb + ((size_t)(b * 8 + head) * 3072 + np) * 32 + dd) = pv;
            }
        }
    }
}

// ---------------------------------------------------------------------------
// K2: attention. S^T = K·Q^T; exp2'd C/D regs form K=32 f16 B-operand for PV
// (V^T as A): out^T[d][q] += V^T·P^T.
// R19: L row-sums moved OFF the VALU onto the MFMA pipe: accL[qg] =
// mfma_f16(ones, pk, accL) — the K=32 reduction covers all lk groups, so the
// 16 fdot2/chunk AND the final shfl_xor reduce are deleted (VALU was the
// largest busy fraction, 40-46%, ~2x MfmaUtil; matrix pipe has headroom at
// 22%). VGPR ~83 < 128 cap (no R17-style spill).
// Per-wave q-tile 64 (4 qg): each kf/vf LDS read feeds 16 MFMAs. KVBLK=128,
// 6 iters, counted-vmcnt dbuf; split-kn=4; XCD swizzle (id&63); (256,4).
__global__ __launch_bounds__(256, 4) void k_attn(const bf16* __restrict__ Q, const bf16* __restrict__ K,
                                                 const f16* __restrict__ Vt,
                                                 f16* __restrict__ Opart, float* __restrict__ Lsum) {
    int id = blockIdx.x;
    int bh = id & 15;
    int sp = (id >> 4) & 3;
    int q0 = (id >> 6) * 256;
    int kn0 = sp * 768;
    int t = threadIdx.x, w = t >> 6, lane = t & 63;
    int lrow = lane & 15, lk = lane >> 4;
    __shared__ __align__(16) char smem[32768];
    bf16* Ks = (bf16*)smem;           // [2][128*32] bf16 (buf stride 4096 elems)
    f16* Vs = (f16*)(smem + 16384);   // [2][2 sub][32*64] f16 (buf stride 4096, sub 2048)
    f16* Tq = (f16*)smem;             // epilogue: per-wave 32 x 66 (aliases Ks)
    const bf16* kbase = K + (size_t)bh * 3072 * 32;
    const f16* vbase = Vt + (size_t)bh * 32 * 3072;
    const bf16* kg = kbase + (size_t)(kn0 + w * 16 + (lane >> 2)) * 32 + (lane & 3) * 8;
    const f16* vg = vbase + (size_t)(w * 8 + (lane >> 3)) * 3072 + kn0 + (lane & 7) * 8;
    // Q as B-operand: B[k=d=lk*8+j][n=q=lrow], one frag per 16-q group
    bf16x8 aq[4];
#pragma unroll
    for (int qg = 0; qg < 4; ++qg)
        aq[qg] = *(const bf16x8*)(Q + ((size_t)bh * 4096 + q0 + w * 64 + qg * 16 + lrow) * 32 + lk * 8);
    f32x4 accO[4][2] = {};   // [q-group][d-half], out^T: row=d_local, col=q
    f32x4 accL[4] = {};      // ones-MFMA row sums (every row = full column sum)
    f32x4 zero = {};
    f16x8 vones;
#pragma unroll
    for (int j = 0; j < 8; ++j) vones[j] = (f16)1.f;
    int vkey = lrow & 7;     // V image XOR key = d&7 (same for both d-halves)
    // prologue: stage tiles 0 and 1 (4 loads each)
    async16(Ks + w * 512, kg);
    async16(Ks + 2048 + w * 512, kg + 64 * 32);
    async16(Vs + w * 512, vg);
    async16(Vs + 2048 + w * 512, vg + 64);
    {
        const bf16* kn_ = kg + 128 * 32;
        const f16* vn_ = vg + 128;
        async16(Ks + 4096 + w * 512, kn_);
        async16(Ks + 4096 + 2048 + w * 512, kn_ + 64 * 32);
        async16(Vs + 4096 + w * 512, vn_);
        async16(Vs + 4096 + 2048 + w * 512, vn_ + 64);
    }
    for (int c = 0; c < 6; ++c) {
        int buf = c & 1;
        // wait for THIS tile's 4 loads; next tile's 4 stay in flight
        if (c < 5) asm volatile("s_waitcnt vmcnt(4)" ::: "memory");
        else       asm volatile("s_waitcnt vmcnt(0)" ::: "memory");
        __builtin_amdgcn_s_barrier();
        __builtin_amdgcn_sched_barrier(0);
        const bf16* ksb = Ks + buf * 4096;
        const f16* vsb0 = Vs + buf * 4096;
#pragma unroll
        for (int p = 0; p < 4; ++p) {   // four 32-kn chunks
            bf16x8 kf0 = *(const bf16x8*)(ksb + (p * 32 + lrow) * 32 + lk * 8);
            bf16x8 kf1 = *(const bf16x8*)(ksb + (p * 32 + 16 + lrow) * 32 + lk * 8);
            const f16* vsb = vsb0 + (p >> 1) * 2048;
            int gran = (((p & 1) << 2) | lk) ^ vkey;
            f16x8 vf0 = *(const f16x8*)(vsb + lrow * 64 + (gran << 3));
            f16x8 vf1 = *(const f16x8*)(vsb + (16 + lrow) * 64 + (gran << 3));
#pragma unroll
            for (int qg = 0; qg < 4; ++qg) {   // kf/vf shared across 4 qg
                f32x4 s0 = MFMA16(kf0, aq[qg], zero, 0, 0, 0);
                f32x4 s1 = MFMA16(kf1, aq[qg], zero, 0, 0, 0);
                f16x2 h0 = pkrtz(__builtin_amdgcn_exp2f(s0[0]), __builtin_amdgcn_exp2f(s0[1]));
                f16x2 h1 = pkrtz(__builtin_amdgcn_exp2f(s0[2]), __builtin_amdgcn_exp2f(s0[3]));
                f16x2 h2 = pkrtz(__builtin_amdgcn_exp2f(s1[0]), __builtin_amdgcn_exp2f(s1[1]));
                f16x2 h3 = pkrtz(__builtin_amdgcn_exp2f(s1[2]), __builtin_amdgcn_exp2f(s1[3]));
                f16x8 pk;
                pk[0] = h0[0]; pk[1] = h0[1]; pk[2] = h1[0]; pk[3] = h1[1];
                pk[4] = h2[0]; pk[5] = h2[1]; pk[6] = h3[0]; pk[7] = h3[1];
                accO[qg][0] = MFMA16H(vf0, pk, accO[qg][0], 0, 0, 0);
                accO[qg][1] = MFMA16H(vf1, pk, accO[qg][1], 0, 0, 0);
                accL[qg]    = MFMA16H(vones, pk, accL[qg], 0, 0, 0);   // row sums on MFMA pipe
            }
        }
        // all LDS reads consumed above; separate read-phase from overwrite
        __builtin_amdgcn_s_barrier();
        if (c < 4) {
            const bf16* kn_ = kg + (size_t)(c + 2) * 128 * 32;
            const f16* vn_ = vg + (c + 2) * 128;
            async16(Ks + buf * 4096 + w * 512, kn_);
            async16(Ks + buf * 4096 + 2048 + w * 512, kn_ + 64 * 32);
            async16(Vs + buf * 4096 + w * 512, vn_);
            async16(Vs + buf * 4096 + 2048 + w * 512, vn_ + 64);
        }
    }
    // L: accL's K=32 MFMA reduction already covers all lk groups — no shuffles.
    int sb = sp * 16 + bh;
    if (lane < 16) {
#pragma unroll
        for (int qg = 0; qg < 4; ++qg)
            Lsum[(size_t)sb * 4096 + q0 + w * 64 + qg * 16 + lane] = accL[qg][0];
    }
    // O epilogue: same-wave LDS transpose [d][q] -> coalesced [q][d] f16 stores
    f16* tw = Tq + w * 2112;   // 32 d-rows x 66 (pad)
#pragma unroll
    for (int qg = 0; qg < 4; ++qg)
#pragma unroll
        for (int dh = 0; dh < 2; ++dh)
#pragma unroll
            for (int i = 0; i < 4; ++i)
                tw[(dh * 16 + lk * 4 + i) * 66 + qg * 16 + lrow] = (f16)accO[qg][dh][i];
    int q4 = (lane & 15) * 4, dgrp = (lane >> 4) * 8;
#pragma unroll
    for (int qq = 0; qq < 4; ++qq) {
        f16x8 ov;
#pragma unroll
        for (int dj = 0; dj < 8; ++dj) ov[dj] = tw[(dgrp + dj) * 66 + q4 + qq];
        *(f16x8*)(Opart + ((size_t)sb * 4096 + q0 + w * 64 + q4 + qq) * 32 + dgrp) = ov;
    }
}

// ---------------------------------------------------------------------------
// K3 "oln": o-projection + split-kn combine + bias + residual + LayerNorm +
// output transpose. 16 q x 256 c blocks (grid 512 = 2 blocks/CU); hoisted
// combine + counted-vmcnt async16 A-staging.
// R19: combine gather widened to f16x8 (same bytes, half the instructions).
__global__ __launch_bounds__(256) void k_oln(const bf16* __restrict__ A, const f16* __restrict__ Opart,
                                             const float* __restrict__ Ls, const float* __restrict__ bias,
                                             const bf16* __restrict__ s3t,
                                             const float* __restrict__ lnw, const float* __restrict__ lnb,
                                             float* __restrict__ out) {
    int i = blockIdx.x;
    int b = i >> 8, n0 = (i & 255) * 16;
    __shared__ __align__(16) char smem[41728];
    bf16* As = (bf16*)smem;                 // [2][256*32] bf16 = 32768 B (async16 dest, linear)
    bf16* Bs = (bf16*)(smem + 32768);       // 16 x 264 bf16 = 8448 B (GEMM phase)
    float* T = (float*)smem;                // 16 x 257 f32 = 16448 B (LN phase, aliases As)
    float* ps = (float*)(smem + 41216);     // [4 w][16 n]
    float* pq = (float*)(smem + 41472);     // [4 w][16 n] (41728 total)
    float* mu_s = (float*)(smem + 16448);   // [16] (aliases As tail, dead by then)
    float* rs_s = (float*)(smem + 16512);   // [16]
    int t = threadIdx.x, w = t >> 6, lane = t & 63;
    int lrow = lane & 15, lk = lane >> 4;
    f32x4 acc[4] = {};                      // [mt: c-64-block], 16-q tile
    const size_t SPS = (size_t)16 * 4096 * 32;   // Opart sp stride (elems)
    // A staging: granule f = (w*4+s)*64 + lane; row = f>>2, col-granule = f&3.
#define STAGE_A(buf_, kc_)                                                              \
    {                                                                                   \
        _Pragma("unroll")                                                               \
        for (int s_ = 0; s_ < 4; ++s_) {                                                \
            int f_ = (w * 4 + s_) * 64 + lane;                                          \
            async16(As + (buf_) * 8192 + f_ * 8,                                        \
                    A + (size_t)(f_ >> 2) * 256 + (kc_) + (f_ & 3) * 8);                \
        }                                                                               \
    }
    STAGE_A(0, 0)
    STAGE_A(1, 32)
    // hoisted combine: B[16 q][256 c] = (sum_sp Opart) / (sum_sp Ls), f16x8 gathers
    {
        int rB = t >> 4;                // 0..15 (q row)
        int q = n0 + rB;
        int gg = t & 15;                // 8-elem granule
#pragma unroll
        for (int cc = 0; cc < 2; ++cc) {
            int c8 = cc * 128 + gg * 8;         // 0..248 step 8
            int bh = b * 8 + (c8 >> 5);
            float lh = 0.f;
#pragma unroll
            for (int sp = 0; sp < 4; ++sp) lh += Ls[(size_t)(sp * 16 + bh) * 4096 + q];
            float rl = 1.0f / lh;
            const f16* obp = Opart + ((size_t)bh * 4096 + q) * 32 + (c8 & 31);
            float sv[8] = {};
#pragma unroll
            for (int sp = 0; sp < 4; ++sp) {
                f16x8 av = *(const f16x8*)(obp + sp * SPS);
#pragma unroll
                for (int j = 0; j < 8; ++j) sv[j] += (float)av[j];
            }
            bf16x8 bb;
#pragma unroll
            for (int j = 0; j < 8; ++j) bb[j] = (bf16)(sv[j] * rl);
            *(bf16x8*)(Bs + rB * 264 + c8) = bb;
        }
    }
    asm volatile("s_waitcnt lgkmcnt(0)" ::: "memory");   // Bs writes drained pre-barrier
    for (int s8 = 0; s8 < 8; ++s8) {
        int buf = s8 & 1;
        int kc = s8 * 32;
        if (s8 < 7) asm volatile("s_waitcnt vmcnt(4)" ::: "memory");
        else        asm volatile("s_waitcnt vmcnt(0)" ::: "memory");
        __builtin_amdgcn_s_barrier();
        __builtin_amdgcn_sched_barrier(0);
        bf16x8 bfr = *(const bf16x8*)(Bs + lrow * 264 + kc + lk * 8);
#pragma unroll
        for (int mt = 0; mt < 4; ++mt) {
            bf16x8 af = *(const bf16x8*)(As + buf * 8192 + (mt * 64 + w * 16 + lrow) * 32 + lk * 8);
            acc[mt] = MFMA16(af, bfr, acc[mt], 0, 0, 0);
        }
        __builtin_amdgcn_s_barrier();
        if (s8 < 6) STAGE_A(buf, (s8 + 2) * 32)
    }
#undef STAGE_A
    // epilogue: bias + residual; write raw values to T; accumulate LN stats
    float wsum = 0.f, wsq = 0.f;
    int n = lrow;
#pragma unroll
    for (int mt = 0; mt < 4; ++mt) {
        int c0 = mt * 64 + w * 16 + lk * 4;
        f32x4 b4 = *(const f32x4*)(bias + c0);
        bf16x4 rv = *(const bf16x4*)(s3t + ((size_t)b * 4096 + n0 + n) * 256 + c0);
#pragma unroll
        for (int j = 0; j < 4; ++j) {
            float v = acc[mt][j] + b4[j] + (float)rv[j];
            T[n * 257 + c0 + j] = v;
            wsum += v;
            wsq += v * v;
        }
    }
    wsum += __shfl_xor(wsum, 16, 64);
    wsum += __shfl_xor(wsum, 32, 64);
    wsq += __shfl_xor(wsq, 16, 64);
    wsq += __shfl_xor(wsq, 32, 64);
    if (lk == 0) {
        ps[w * 16 + lrow] = wsum;
        pq[w * 16 + lrow] = wsq;
    }
    __syncthreads();
    if (t < 16) {
        float S = ps[t] + ps[16 + t] + ps[32 + t] + ps[48 + t];
        float Q2 = pq[t] + pq[16 + t] + pq[32 + t] + pq[48 + t];
        float m = S * (1.0f / 256.0f);
        mu_s[t] = m;
        rs_s[t] = rsqrtf(Q2 * (1.0f / 256.0f) - m * m + 1e-5f);
    }
    __syncthreads();
    // write out[b][c][n0..n0+15], coalesced along n
    int cb = t >> 2, n4 = (t & 3) * 4;
#pragma unroll
    for (int cc4 = 0; cc4 < 4; ++cc4) {
        int c = cb + cc4 * 64;
        float wv = lnw[c], bv = lnb[c];
        f32x4 o;
#pragma unroll
        for (int k2 = 0; k2 < 4; ++k2)
            o[k2] = (T[(n4 + k2) * 257 + c] - mu_s[n4 + k2]) * rs_s[n4 + k2] * wv + bv;
        *(f32x4*)(out + ((size_t)b * 256 + c) * 4096 + n0 + n4) = o;
    }
}

// ---------------------------------------------------------------------------
extern "C" void kernel_launch(void* const* d_in, const int* in_sizes, int n_in,
                              void* d_out, int out_size, void* d_ws, size_t ws_size,
                              hipStream_t stream) {
    const float* s3  = (const float*)d_in[0];
    const float* s4  = (const float*)d_in[1];
    const float* s5  = (const float*)d_in[2];
    const float* qw  = (const float*)d_in[3];
    const float* qb  = (const float*)d_in[4];
    const float* kw  = (const float*)d_in[5];
    const float* kb  = (const float*)d_in[6];
    const float* vw  = (const float*)d_in[7];
    const float* vb  = (const float*)d_in[8];
    const float* ow  = (const float*)d_in[9];
    const float* ob  = (const float*)d_in[10];
    const float* lnw = (const float*)d_in[11];
    const float* lnb = (const float*)d_in[12];
    float* out = (float*)d_out;
    char* ws = (char*)d_ws;

    // workspace layout (~34.5 MB peak):
    bf16* Wb    = (bf16*)(ws);                          // 512 KB @ 0
    bf16* s3t   = (bf16*)(ws + (512ull << 10));         // 4 MB  @ 0.5 MB (live till k_oln)
    bf16* s45t  = (bf16*)(ws + (4608ull << 10));        // 3 MB  @ 4.5 MB
    bf16* Qb    = (bf16*)(ws + (7680ull << 10));        // 4 MB  @ 7.5 MB
    bf16* Kb    = Qb + (2ull * 8 * 4096 * 32);          // 3 MB  @ 11.5 MB
    f16*  Vtb   = (f16*)(Kb + (2ull * 8 * 3072 * 32));  // 3 MB  @ 14.5 MB
    f16*  Opart = (f16*)(ws + (17920ull << 10));        // 16 MB @ 17.5 MB (f16 [4sp][16bh][4096q][32d])
    float* Lsum = (float*)(ws + (34304ull << 10));      // 1 MB  @ 33.5 MB

    const float qscale = 0.17677669529663688f * 1.4426950408889634f;  // 32^-0.5 * log2(e)

    k_prep<<<1152, 256, 0, stream>>>(qw, kw, vw, ow, Wb, s3, s4, s5, s3t, s45t);
    k_qkv<<<1280, 256, 0, stream>>>(Wb, s3t, s45t, qb, kb, vb, Qb, Kb, Vtb, qscale);
    k_attn<<<1024, 256, 0, stream>>>(Qb, Kb, Vtb, Opart, Lsum);
    k_oln<<<512, 256, 0, stream>>>(Wb + 196608, Opart, Lsum, ob, s3t, lnw, lnb, out);
}

// Round 11
// 136.855 us; speedup vs baseline: 1.6247x; 1.0115x over previous
//
#include <hip/hip_runtime.h>

typedef __bf16 bf16;
typedef __bf16 bf16x4 __attribute__((ext_vector_type(4)));
typedef __bf16 bf16x8 __attribute__((ext_vector_type(8)));
typedef _Float16 f16;
typedef _Float16 f16x2 __attribute__((ext_vector_type(2)));
typedef _Float16 f16x4 __attribute__((ext_vector_type(4)));
typedef _Float16 f16x8 __attribute__((ext_vector_type(8)));
typedef float f32x4 __attribute__((ext_vector_type(4)));
typedef unsigned int u32x4 __attribute__((ext_vector_type(4)));

#define MFMA16 __builtin_amdgcn_mfma_f32_16x16x32_bf16
#define MFMA16H __builtin_amdgcn_mfma_f32_16x16x32_f16

// async 16B/lane global->LDS copy; HW scatters lane i to lds + i*16 (wave-uniform base)
__device__ __forceinline__ void async16(void* lds, const void* g) {
    __builtin_amdgcn_global_load_lds((const __attribute__((address_space(1))) unsigned int*)g,
                                     (__attribute__((address_space(3))) unsigned int*)lds, 16, 0, 0);
}

// packed f32x2 -> f16x2 (cvt_pkrtz returns __fp16-based vector; bit-cast to _Float16-based)
__device__ __forceinline__ f16x2 pkrtz(float a, float b) {
    return __builtin_bit_cast(f16x2, __builtin_amdgcn_cvt_pkrtz(a, b));
}

// ---------------------------------------------------------------------------
// K0 "prep": weight cvt (blocks 0..255) + three activation transposes
// (s3: 256..767, s4: 768..1023, s5: 1024..1151).
// R20: transpose store phase widened to bf16x8 (16B stores, half the insts).
__global__ __launch_bounds__(256) void k_prep(const float* __restrict__ qw, const float* __restrict__ kw,
                                              const float* __restrict__ vw, const float* __restrict__ ow,
                                              bf16* __restrict__ Wb,
                                              const float* __restrict__ s3, const float* __restrict__ s4,
                                              const float* __restrict__ s5,
                                              bf16* __restrict__ s3t, bf16* __restrict__ s45t) {
    __shared__ float T[64][65];
    int bx = blockIdx.x, t = threadIdx.x;
    if (bx < 256) {
        int tt = bx * 256 + t;
        const float* srcs[4] = {qw, kw, vw, ow};
        int which = tt >> 14;
        int idx = (tt & 16383) * 4;
        f32x4 v = *(const f32x4*)(srcs[which] + idx);
        bf16x4 o;
        o[0] = (bf16)v[0]; o[1] = (bf16)v[1]; o[2] = (bf16)v[2]; o[3] = (bf16)v[3];
        *(bf16x4*)(Wb + (size_t)which * 65536 + idx) = o;
        return;
    }
    const float* src; bf16* dst; int N, dstRows, rowOff, x, y, z;
    if (bx < 768)       { int i = bx - 256;  src = s3; dst = s3t;  N = 4096; dstRows = 4096; rowOff = 0;    x = i & 63; y = (i >> 6) & 3; z = i >> 8; }
    else if (bx < 1024) { int i = bx - 768;  src = s4; dst = s45t; N = 2048; dstRows = 3072; rowOff = 0;    x = i & 31; y = (i >> 5) & 3; z = i >> 7; }
    else                { int i = bx - 1024; src = s5; dst = s45t; N = 1024; dstRows = 3072; rowOff = 2048; x = i & 15; y = (i >> 4) & 3; z = i >> 6; }
    int c0 = y * 64, n0 = x * 64, b = z;
    const float* s = src + ((size_t)b * 256 + c0) * N + n0;
#pragma unroll
    for (int i = 0; i < 4; i++) {
        int flat = i * 256 + t;
        int row = flat >> 4;
        int col = (flat & 15) * 4;
        f32x4 v = *(const f32x4*)(s + (size_t)row * N + col);
        T[row][col + 0] = v[0]; T[row][col + 1] = v[1];
        T[row][col + 2] = v[2]; T[row][col + 3] = v[3];
    }
    __syncthreads();
#pragma unroll
    for (int i = 0; i < 2; i++) {
        int flat = i * 256 + t;
        int nrow = flat >> 3;
        int c8 = (flat & 7) * 8;
        bf16x8 o;
#pragma unroll
        for (int j = 0; j < 8; j++) o[j] = (bf16)T[c8 + j][nrow];
        *(bf16x8*)(dst + ((size_t)(b * dstRows + rowOff + n0 + nrow)) * 256 + c0 + c8) = o;
    }
}

// ---------------------------------------------------------------------------
// K1 "qkv": Q blocks 0..511 (mode 0), K 512..895 (mode 1), V 896..1279 (mode 2).
// mode 0: Q bf16 [bh][n][32], pre-scaled by 32^-.5*log2e.
// mode 1: K bf16 [bh][n'][32], n' row-permuted within 32-blocks.
// mode 2: V f16 [bh][32 d][3072 kn], kn permuted per 64-chunk by d-keyed XOR;
// operand-swapped MFMA (D^T) -> 4x f16x4 stores.
// R20: BK 32 -> 64 (4 K-steps, barriers 16 -> 8, 8 MFMA/wave/step; LDS 32KB
// keeps the 5 blocks/CU the grid needs). 64-col rows are 128B = the genuine
// all-rows-same-bank b128 conflict, so the LDS image is XOR-swizzled via the
// per-lane GLOBAL source granule ((lane&7)^(lane>>3)); reads XOR with lrow&7.
// Counted-vmcnt dbuf: 4 loads/step, vmcnt(4).
__global__ __launch_bounds__(256) void k_qkv(const bf16* __restrict__ Wb,
                                             const bf16* __restrict__ s3t, const bf16* __restrict__ s45t,
                                             const float* __restrict__ qb, const float* __restrict__ kb,
                                             const float* __restrict__ vb,
                                             bf16* __restrict__ Qb, bf16* __restrict__ Kb,
                                             f16* __restrict__ Vtb, float qscale) {
    int i = blockIdx.x;
    int mode, n0, m0, b, Nrows;
    const bf16 *A, *Bt; const float* bias; float oscale = 1.0f;
    if (i < 512) {
        mode = 0; A = Wb; Bt = s3t; bias = qb; Nrows = 4096; oscale = qscale;
        n0 = (i & 63) * 64; m0 = ((i >> 6) & 3) * 64; b = i >> 8;
    } else if (i < 896) {
        unsigned j = i - 512;
        mode = 1; A = Wb + 65536; Bt = s45t; bias = kb; Nrows = 3072;
        n0 = (j % 48u) * 64; unsigned rr = j / 48u; m0 = (rr & 3) * 64; b = rr >> 2;
    } else {
        unsigned j = i - 896;
        mode = 2; A = Wb + 131072; Bt = s45t; bias = vb; Nrows = 3072;
        n0 = (j % 48u) * 64; unsigned rr = j / 48u; m0 = (rr & 3) * 64; b = rr >> 2;
    }
    __shared__ __align__(16) bf16 As[2][64 * 64];
    __shared__ __align__(16) bf16 Bs[2][64 * 64];
    int t = threadIdx.x;
    int w = t >> 6, lane = t & 63;
    int lrow = lane & 15, lk = lane >> 4;
    f32x4 acc[4] = {};
    int r8 = lane >> 3;                // 0..7 sub-row within the wave's 16-row span... (2 spans of 8)
    int g8 = (lane & 7) ^ (r8 & 7);    // pre-swizzled source granule (read XORs with row&7)
    // per-lane global sources: two 8-row spans per wave (s=0: rows w*16+r8, s=1: +8)
    const bf16* Ag0 = A + (size_t)(m0 + w * 16 + r8) * 256 + g8 * 8;
    const bf16* Ag1 = Ag0 + 8 * 256;
    const bf16* Bg0 = Bt + ((size_t)b * Nrows + n0 + w * 16 + r8) * 256 + g8 * 8;
    const bf16* Bg1 = Bg0 + 8 * 256;
    // stage (buf, kc): 4 async16/thread; LDS linear [row][64]
#define STAGE_QKV(buf_, kc_)                                        \
    {                                                               \
        async16(&As[buf_][(w * 16) * 64], Ag0 + (kc_));             \
        async16(&As[buf_][(w * 16 + 8) * 64], Ag1 + (kc_));         \
        async16(&Bs[buf_][(w * 16) * 64], Bg0 + (kc_));             \
        async16(&Bs[buf_][(w * 16 + 8) * 64], Bg1 + (kc_));         \
    }
    STAGE_QKV(0, 0)
    STAGE_QKV(1, 64)
    int keyA = lrow & 7;
    for (int s4 = 0; s4 < 4; ++s4) {
        int buf = s4 & 1;
        if (s4 < 3) asm volatile("s_waitcnt vmcnt(4)" ::: "memory");
        else        asm volatile("s_waitcnt vmcnt(0)" ::: "memory");
        __builtin_amdgcn_s_barrier();
        __builtin_amdgcn_sched_barrier(0);
        bf16x8 af0 = *(const bf16x8*)(&As[buf][(w * 16 + lrow) * 64 + ((lk ^ keyA) << 3)]);
        bf16x8 af1 = *(const bf16x8*)(&As[buf][(w * 16 + lrow) * 64 + (((4 + lk) ^ keyA) << 3)]);
#pragma unroll
        for (int ct = 0; ct < 4; ct++) {
            bf16x8 b0 = *(const bf16x8*)(&Bs[buf][(ct * 16 + lrow) * 64 + ((lk ^ keyA) << 3)]);
            bf16x8 b1 = *(const bf16x8*)(&Bs[buf][(ct * 16 + lrow) * 64 + (((4 + lk) ^ keyA) << 3)]);
            if (mode == 2) {
                acc[ct] = MFMA16(b0, af0, acc[ct], 0, 0, 0);   // D^T: rows=n, cols=o
                acc[ct] = MFMA16(b1, af1, acc[ct], 0, 0, 0);
            } else {
                acc[ct] = MFMA16(af0, b0, acc[ct], 0, 0, 0);   // rows=o, cols=n
                acc[ct] = MFMA16(af1, b1, acc[ct], 0, 0, 0);
            }
        }
        __builtin_amdgcn_s_barrier();
        if (s4 < 2) STAGE_QKV(buf, (s4 + 2) * 64)
    }
#undef STAGE_QKV
    // C/D layout: col = lane&15, row = (lane>>4)*4 + reg  [verified m89/m91]
    if (mode == 2) {
        // lane: o = m0 + w*16 + lrow (fixed), n = n0 + ct*16 + lk*4 + j (consecutive)
        int o = m0 + w * 16 + lrow;
        int head = o >> 5;
        int dd = o & 31;
        float bs = bias[o];
        int key = dd & 7;
        f16* vrow = Vtb + ((size_t)(b * 8 + head) * 32 + dd) * 3072;
#pragma unroll
        for (int ct = 0; ct < 4; ct++) {
            int g = ct * 2 + (lk >> 1);                       // 8-elem granule of n&63
            int col = n0 + ((g ^ key) << 3) + (lk & 1) * 4;   // XOR-permuted position
            f16x4 pv;
#pragma unroll
            for (int j = 0; j < 4; j++) pv[j] = (f16)(acc[ct][j] + bs);
            *(f16x4*)(vrow + col) = pv;
        }
    } else {
        int o0 = m0 + w * 16 + lk * 4;
        f32x4 b4 = *(const f32x4*)(bias + o0);
        int head = o0 >> 5;
#pragma unroll
        for (int ct = 0; ct < 4; ct++) {
            int n = n0 + ct * 16 + lrow;
            if (mode == 0) {
                int dd = o0 & 31;
                bf16x4 pv;
#pragma unroll
                for (int j = 0; j < 4; j++) pv[j] = (bf16)((acc[ct][j] + b4[j]) * oscale);
                *(bf16x4*)(Qb + ((size_t)(b * 8 + head) * 4096 + n) * 32 + dd) = pv;
            } else {
                int dd = o0 & 31;
                int u = n & 31;
                int np = (n & ~31) | (((u >> 2) & 1) << 4) | ((u >> 3) << 2) | (u & 3);
                bf16x4 pv;
#pragma unroll
                for (int j = 0; j < 4; j++) pv[j] = (bf16)(acc[ct][j] + b4[j]);
                *(bf16x4*)(Kb + ((size_t)(b * 8 + head) * 3072 + np) * 32 + dd) = pv;
            }
        }
    }
}

// ---------------------------------------------------------------------------
// K2: attention (R19 config, unchanged). S^T = K·Q^T; exp2'd C/D regs form
// K=32 f16 B-operand for PV (V^T as A): out^T[d][q] += V^T·P^T.
// L row-sums on the MFMA pipe via ones-MFMA (no fdot2, no shuffles).
// Per-wave q-tile 64 (4 qg); KVBLK=128, 6 iters, counted-vmcnt dbuf;
// split-kn=4; XCD swizzle (id&63); (256,4), VGPR ~83 (no spill).
__global__ __launch_bounds__(256, 4) void k_attn(const bf16* __restrict__ Q, const bf16* __restrict__ K,
                                                 const f16* __restrict__ Vt,
                                                 f16* __restrict__ Opart, float* __restrict__ Lsum) {
    int id = blockIdx.x;
    int bh = id & 15;
    int sp = (id >> 4) & 3;
    int q0 = (id >> 6) * 256;
    int kn0 = sp * 768;
    int t = threadIdx.x, w = t >> 6, lane = t & 63;
    int lrow = lane & 15, lk = lane >> 4;
    __shared__ __align__(16) char smem[32768];
    bf16* Ks = (bf16*)smem;           // [2][128*32] bf16 (buf stride 4096 elems)
    f16* Vs = (f16*)(smem + 16384);   // [2][2 sub][32*64] f16 (buf stride 4096, sub 2048)
    f16* Tq = (f16*)smem;             // epilogue: per-wave 32 x 66 (aliases Ks)
    const bf16* kbase = K + (size_t)bh * 3072 * 32;
    const f16* vbase = Vt + (size_t)bh * 32 * 3072;
    const bf16* kg = kbase + (size_t)(kn0 + w * 16 + (lane >> 2)) * 32 + (lane & 3) * 8;
    const f16* vg = vbase + (size_t)(w * 8 + (lane >> 3)) * 3072 + kn0 + (lane & 7) * 8;
    // Q as B-operand: B[k=d=lk*8+j][n=q=lrow], one frag per 16-q group
    bf16x8 aq[4];
#pragma unroll
    for (int qg = 0; qg < 4; ++qg)
        aq[qg] = *(const bf16x8*)(Q + ((size_t)bh * 4096 + q0 + w * 64 + qg * 16 + lrow) * 32 + lk * 8);
    f32x4 accO[4][2] = {};   // [q-group][d-half], out^T: row=d_local, col=q
    f32x4 accL[4] = {};      // ones-MFMA row sums (every row = full column sum)
    f32x4 zero = {};
    f16x8 vones;
#pragma unroll
    for (int j = 0; j < 8; ++j) vones[j] = (f16)1.f;
    int vkey = lrow & 7;     // V image XOR key = d&7 (same for both d-halves)
    // prologue: stage tiles 0 and 1 (4 loads each)
    async16(Ks + w * 512, kg);
    async16(Ks + 2048 + w * 512, kg + 64 * 32);
    async16(Vs + w * 512, vg);
    async16(Vs + 2048 + w * 512, vg + 64);
    {
        const bf16* kn_ = kg + 128 * 32;
        const f16* vn_ = vg + 128;
        async16(Ks + 4096 + w * 512, kn_);
        async16(Ks + 4096 + 2048 + w * 512, kn_ + 64 * 32);
        async16(Vs + 4096 + w * 512, vn_);
        async16(Vs + 4096 + 2048 + w * 512, vn_ + 64);
    }
    for (int c = 0; c < 6; ++c) {
        int buf = c & 1;
        // wait for THIS tile's 4 loads; next tile's 4 stay in flight
        if (c < 5) asm volatile("s_waitcnt vmcnt(4)" ::: "memory");
        else       asm volatile("s_waitcnt vmcnt(0)" ::: "memory");
        __builtin_amdgcn_s_barrier();
        __builtin_amdgcn_sched_barrier(0);
        const bf16* ksb = Ks + buf * 4096;
        const f16* vsb0 = Vs + buf * 4096;
#pragma unroll
        for (int p = 0; p < 4; ++p) {   // four 32-kn chunks
            bf16x8 kf0 = *(const bf16x8*)(ksb + (p * 32 + lrow) * 32 + lk * 8);
            bf16x8 kf1 = *(const bf16x8*)(ksb + (p * 32 + 16 + lrow) * 32 + lk * 8);
            const f16* vsb = vsb0 + (p >> 1) * 2048;
            int gran = (((p & 1) << 2) | lk) ^ vkey;
            f16x8 vf0 = *(const f16x8*)(vsb + lrow * 64 + (gran << 3));
            f16x8 vf1 = *(const f16x8*)(vsb + (16 + lrow) * 64 + (gran << 3));
#pragma unroll
            for (int qg = 0; qg < 4; ++qg) {   // kf/vf shared across 4 qg
                f32x4 s0 = MFMA16(kf0, aq[qg], zero, 0, 0, 0);
                f32x4 s1 = MFMA16(kf1, aq[qg], zero, 0, 0, 0);
                f16x2 h0 = pkrtz(__builtin_amdgcn_exp2f(s0[0]), __builtin_amdgcn_exp2f(s0[1]));
                f16x2 h1 = pkrtz(__builtin_amdgcn_exp2f(s0[2]), __builtin_amdgcn_exp2f(s0[3]));
                f16x2 h2 = pkrtz(__builtin_amdgcn_exp2f(s1[0]), __builtin_amdgcn_exp2f(s1[1]));
                f16x2 h3 = pkrtz(__builtin_amdgcn_exp2f(s1[2]), __builtin_amdgcn_exp2f(s1[3]));
                f16x8 pk;
                pk[0] = h0[0]; pk[1] = h0[1]; pk[2] = h1[0]; pk[3] = h1[1];
                pk[4] = h2[0]; pk[5] = h2[1]; pk[6] = h3[0]; pk[7] = h3[1];
                accO[qg][0] = MFMA16H(vf0, pk, accO[qg][0], 0, 0, 0);
                accO[qg][1] = MFMA16H(vf1, pk, accO[qg][1], 0, 0, 0);
                accL[qg]    = MFMA16H(vones, pk, accL[qg], 0, 0, 0);   // row sums on MFMA pipe
            }
        }
        // all LDS reads consumed above; separate read-phase from overwrite
        __builtin_amdgcn_s_barrier();
        if (c < 4) {
            const bf16* kn_ = kg + (size_t)(c + 2) * 128 * 32;
            const f16* vn_ = vg + (c + 2) * 128;
            async16(Ks + buf * 4096 + w * 512, kn_);
            async16(Ks + buf * 4096 + 2048 + w * 512, kn_ + 64 * 32);
            async16(Vs + buf * 4096 + w * 512, vn_);
            async16(Vs + buf * 4096 + 2048 + w * 512, vn_ + 64);
        }
    }
    // L: accL's K=32 MFMA reduction already covers all lk groups — no shuffles.
    int sb = sp * 16 + bh;
    if (lane < 16) {
#pragma unroll
        for (int qg = 0; qg < 4; ++qg)
            Lsum[(size_t)sb * 4096 + q0 + w * 64 + qg * 16 + lane] = accL[qg][0];
    }
    // O epilogue: same-wave LDS transpose [d][q] -> coalesced [q][d] f16 stores
    f16* tw = Tq + w * 2112;   // 32 d-rows x 66 (pad)
#pragma unroll
    for (int qg = 0; qg < 4; ++qg)
#pragma unroll
        for (int dh = 0; dh < 2; ++dh)
#pragma unroll
            for (int i = 0; i < 4; ++i)
                tw[(dh * 16 + lk * 4 + i) * 66 + qg * 16 + lrow] = (f16)accO[qg][dh][i];
    int q4 = (lane & 15) * 4, dgrp = (lane >> 4) * 8;
#pragma unroll
    for (int qq = 0; qq < 4; ++qq) {
        f16x8 ov;
#pragma unroll
        for (int dj = 0; dj < 8; ++dj) ov[dj] = tw[(dgrp + dj) * 66 + q4 + qq];
        *(f16x8*)(Opart + ((size_t)sb * 4096 + q0 + w * 64 + q4 + qq) * 32 + dgrp) = ov;
    }
}

// ---------------------------------------------------------------------------
// K3 "oln": o-projection + split-kn combine + bias + residual + LayerNorm +
// output transpose (R19 config, unchanged). 16 q x 256 c blocks (grid 512 =
// 2 blocks/CU); hoisted combine (f16x8 gathers) + counted-vmcnt async16
// A-staging.
__global__ __launch_bounds__(256) void k_oln(const bf16* __restrict__ A, const f16* __restrict__ Opart,
                                             const float* __restrict__ Ls, const float* __restrict__ bias,
                                             const bf16* __restrict__ s3t,
                                             const float* __restrict__ lnw, const float* __restrict__ lnb,
                                             float* __restrict__ out) {
    int i = blockIdx.x;
    int b = i >> 8, n0 = (i & 255) * 16;
    __shared__ __align__(16) char smem[41728];
    bf16* As = (bf16*)smem;                 // [2][256*32] bf16 = 32768 B (async16 dest, linear)
    bf16* Bs = (bf16*)(smem + 32768);       // 16 x 264 bf16 = 8448 B (GEMM phase)
    float* T = (float*)smem;                // 16 x 257 f32 = 16448 B (LN phase, aliases As)
    float* ps = (float*)(smem + 41216);     // [4 w][16 n]
    float* pq = (float*)(smem + 41472);     // [4 w][16 n] (41728 total)
    float* mu_s = (float*)(smem + 16448);   // [16] (aliases As tail, dead by then)
    float* rs_s = (float*)(smem + 16512);   // [16]
    int t = threadIdx.x, w = t >> 6, lane = t & 63;
    int lrow = lane & 15, lk = lane >> 4;
    f32x4 acc[4] = {};                      // [mt: c-64-block], 16-q tile
    const size_t SPS = (size_t)16 * 4096 * 32;   // Opart sp stride (elems)
    // A staging: granule f = (w*4+s)*64 + lane; row = f>>2, col-granule = f&3.
#define STAGE_A(buf_, kc_)                                                              \
    {                                                                                   \
        _Pragma("unroll")                                                               \
        for (int s_ = 0; s_ < 4; ++s_) {                                                \
            int f_ = (w * 4 + s_) * 64 + lane;                                          \
            async16(As + (buf_) * 8192 + f_ * 8,                                        \
                    A + (size_t)(f_ >> 2) * 256 + (kc_) + (f_ & 3) * 8);                \
        }                                                                               \
    }
    STAGE_A(0, 0)
    STAGE_A(1, 32)
    // hoisted combine: B[16 q][256 c] = (sum_sp Opart) / (sum_sp Ls), f16x8 gathers
    {
        int rB = t >> 4;                // 0..15 (q row)
        int q = n0 + rB;
        int gg = t & 15;                // 8-elem granule
#pragma unroll
        for (int cc = 0; cc < 2; ++cc) {
            int c8 = cc * 128 + gg * 8;         // 0..248 step 8
            int bh = b * 8 + (c8 >> 5);
            float lh = 0.f;
#pragma unroll
            for (int sp = 0; sp < 4; ++sp) lh += Ls[(size_t)(sp * 16 + bh) * 4096 + q];
            float rl = 1.0f / lh;
            const f16* obp = Opart + ((size_t)bh * 4096 + q) * 32 + (c8 & 31);
            float sv[8] = {};
#pragma unroll
            for (int sp = 0; sp < 4; ++sp) {
                f16x8 av = *(const f16x8*)(obp + sp * SPS);
#pragma unroll
                for (int j = 0; j < 8; ++j) sv[j] += (float)av[j];
            }
            bf16x8 bb;
#pragma unroll
            for (int j = 0; j < 8; ++j) bb[j] = (bf16)(sv[j] * rl);
            *(bf16x8*)(Bs + rB * 264 + c8) = bb;
        }
    }
    asm volatile("s_waitcnt lgkmcnt(0)" ::: "memory");   // Bs writes drained pre-barrier
    for (int s8 = 0; s8 < 8; ++s8) {
        int buf = s8 & 1;
        int kc = s8 * 32;
        if (s8 < 7) asm volatile("s_waitcnt vmcnt(4)" ::: "memory");
        else        asm volatile("s_waitcnt vmcnt(0)" ::: "memory");
        __builtin_amdgcn_s_barrier();
        __builtin_amdgcn_sched_barrier(0);
        bf16x8 bfr = *(const bf16x8*)(Bs + lrow * 264 + kc + lk * 8);
#pragma unroll
        for (int mt = 0; mt < 4; ++mt) {
            bf16x8 af = *(const bf16x8*)(As + buf * 8192 + (mt * 64 + w * 16 + lrow) * 32 + lk * 8);
            acc[mt] = MFMA16(af, bfr, acc[mt], 0, 0, 0);
        }
        __builtin_amdgcn_s_barrier();
        if (s8 < 6) STAGE_A(buf, (s8 + 2) * 32)
    }
#undef STAGE_A
    // epilogue: bias + residual; write raw values to T; accumulate LN stats
    float wsum = 0.f, wsq = 0.f;
    int n = lrow;
#pragma unroll
    for (int mt = 0; mt < 4; ++mt) {
        int c0 = mt * 64 + w * 16 + lk * 4;
        f32x4 b4 = *(const f32x4*)(bias + c0);
        bf16x4 rv = *(const bf16x4*)(s3t + ((size_t)b * 4096 + n0 + n) * 256 + c0);
#pragma unroll
        for (int j = 0; j < 4; ++j) {
            float v = acc[mt][j] + b4[j] + (float)rv[j];
            T[n * 257 + c0 + j] = v;
            wsum += v;
            wsq += v * v;
        }
    }
    wsum += __shfl_xor(wsum, 16, 64);
    wsum += __shfl_xor(wsum, 32, 64);
    wsq += __shfl_xor(wsq, 16, 64);
    wsq += __shfl_xor(wsq, 32, 64);
    if (lk == 0) {
        ps[w * 16 + lrow] = wsum;
        pq[w * 16 + lrow] = wsq;
    }
    __syncthreads();
    if (t < 16) {
        float S = ps[t] + ps[16 + t] + ps[32 + t] + ps[48 + t];
        float Q2 = pq[t] + pq[16 + t] + pq[32 + t] + pq[48 + t];
        float m = S * (1.0f / 256.0f);
        mu_s[t] = m;
        rs_s[t] = rsqrtf(Q2 * (1.0f / 256.0f) - m * m + 1e-5f);
    }
    __syncthreads();
    // write out[b][c][n0..n0+15], coalesced along n
    int cb = t >> 2, n4 = (t & 3) * 4;
#pragma unroll
    for (int cc4 = 0; cc4 < 4; ++cc4) {
        int c = cb + cc4 * 64;
        float wv = lnw[c], bv = lnb[c];
        f32x4 o;
#pragma unroll
        for (int k2 = 0; k2 < 4; ++k2)
            o[k2] = (T[(n4 + k2) * 257 + c] - mu_s[n4 + k2]) * rs_s[n4 + k2] * wv + bv;
        *(f32x4*)(out + ((size_t)b * 256 + c) * 4096 + n0 + n4) = o;
    }
}

// ---------------------------------------------------------------------------
extern "C" void kernel_launch(void* const* d_in, const int* in_sizes, int n_in,
                              void* d_out, int out_size, void* d_ws, size_t ws_size,
                              hipStream_t stream) {
    const float* s3  = (const float*)d_in[0];
    const float* s4  = (const float*)d_in[1];
    const float* s5  = (const float*)d_in[2];
    const float* qw  = (const float*)d_in[3];
    const float* qb  = (const float*)d_in[4];
    const float* kw  = (const float*)d_in[5];
    const float* kb  = (const float*)d_in[6];
    const float* vw  = (const float*)d_in[7];
    const float* vb  = (const float*)d_in[8];
    const float* ow  = (const float*)d_in[9];
    const float* ob  = (const float*)d_in[10];
    const float* lnw = (const float*)d_in[11];
    const float* lnb = (const float*)d_in[12];
    float* out = (float*)d_out;
    char* ws = (char*)d_ws;

    // workspace layout (~34.5 MB peak):
    bf16* Wb    = (bf16*)(ws);                          // 512 KB @ 0
    bf16* s3t   = (bf16*)(ws + (512ull << 10));         // 4 MB  @ 0.5 MB (live till k_oln)
    bf16* s45t  = (bf16*)(ws + (4608ull << 10));        // 3 MB  @ 4.5 MB
    bf16* Qb    = (bf16*)(ws + (7680ull << 10));        // 4 MB  @ 7.5 MB
    bf16* Kb    = Qb + (2ull * 8 * 4096 * 32);          // 3 MB  @ 11.5 MB
    f16*  Vtb   = (f16*)(Kb + (2ull * 8 * 3072 * 32));  // 3 MB  @ 14.5 MB
    f16*  Opart = (f16*)(ws + (17920ull << 10));        // 16 MB @ 17.5 MB (f16 [4sp][16bh][4096q][32d])
    float* Lsum = (float*)(ws + (34304ull << 10));      // 1 MB  @ 33.5 MB

    const float qscale = 0.17677669529663688f * 1.4426950408889634f;  // 32^-0.5 * log2(e)

    k_prep<<<1152, 256, 0, stream>>>(qw, kw, vw, ow, Wb, s3, s4, s5, s3t, s45t);
    k_qkv<<<1280, 256, 0, stream>>>(Wb, s3t, s45t, qb, kb, vb, Qb, Kb, Vtb, qscale);
    k_attn<<<1024, 256, 0, stream>>>(Qb, Kb, Vtb, Opart, Lsum);
    k_oln<<<512, 256, 0, stream>>>(Wb + 196608, Opart, Lsum, ob, s3t, lnw, lnb, out);
}